// Round 1
// baseline (1079.339 us; speedup 1.0000x reference)
//
#include <hip/hip_runtime.h>
#include <math.h>

// Problem constants (derived from reference): N=20000, E=320000, HID=128, L=32
constexpr int GBM = 128, GBN = 64, GBK = 32;

__device__ __forceinline__ float silu_f(float x) { return x / (1.f + __expf(-x)); }
__device__ __forceinline__ float gelu_f(float x) {
    float x3 = x * x * x;
    return 0.5f * x * (1.f + tanhf(0.7978845608028654f * (x + 0.044715f * x3)));
}

// ---------------------------------------------------------------------------
// Generic tiled fp32 GEMM: C = epi(pre(A) @ W + bias)
// PRE: 0=none 1=silu    EPI: 0=none 1=gelu 2=res+val 3=res+gate*val
// ---------------------------------------------------------------------------
template<int PRE, int EPI>
__global__ __launch_bounds__(256) void gemm_kernel(
    const float* __restrict__ A, const float* __restrict__ W,
    const float* __restrict__ bias, float* __restrict__ C,
    const float* __restrict__ res, const float* __restrict__ gate,
    int N, int K, int M)
{
    __shared__ float As[GBK][GBM + 4];   // A transposed: As[k][m]
    __shared__ float Ws[GBK][GBN];
    const int tid = threadIdx.x;
    const int row0 = blockIdx.x * GBM;
    const int col0 = blockIdx.y * GBN;
    const int ty = tid >> 4, tx = tid & 15;
    float acc[8][4];
#pragma unroll
    for (int i = 0; i < 8; i++)
#pragma unroll
        for (int j = 0; j < 4; j++) acc[i][j] = 0.f;

    for (int k0 = 0; k0 < K; k0 += GBK) {
#pragma unroll
        for (int i = 0; i < 16; i++) {
            int f = tid + i * 256;
            int m = f >> 5, kk = f & 31;
            int r = row0 + m;
            float v = 0.f;
            if (r < N) {
                v = A[(size_t)r * K + k0 + kk];
                if (PRE == 1) v = silu_f(v);
            }
            As[kk][m] = v;
        }
#pragma unroll
        for (int i = 0; i < 8; i++) {
            int f = tid + i * 256;
            int kk = f >> 6, c = f & 63;
            Ws[kk][c] = W[(size_t)(k0 + kk) * M + col0 + c];
        }
        __syncthreads();
#pragma unroll
        for (int kk = 0; kk < GBK; kk++) {
            float4 a0 = *(const float4*)&As[kk][ty * 8];
            float4 a1 = *(const float4*)&As[kk][ty * 8 + 4];
            float4 w  = *(const float4*)&Ws[kk][tx * 4];
            float av[8] = {a0.x, a0.y, a0.z, a0.w, a1.x, a1.y, a1.z, a1.w};
            float wv[4] = {w.x, w.y, w.z, w.w};
#pragma unroll
            for (int i = 0; i < 8; i++)
#pragma unroll
                for (int j = 0; j < 4; j++)
                    acc[i][j] = fmaf(av[i], wv[j], acc[i][j]);
        }
        __syncthreads();
    }
#pragma unroll
    for (int i = 0; i < 8; i++) {
        int r = row0 + ty * 8 + i;
        if (r >= N) continue;
#pragma unroll
        for (int j = 0; j < 4; j++) {
            int c = col0 + tx * 4 + j;
            float val = acc[i][j] + bias[c];
            size_t idx = (size_t)r * M + c;
            if (EPI == 1) val = gelu_f(val);
            else if (EPI == 2) val = res[idx] + val;
            else if (EPI == 3) val = res[idx] + gate[(size_t)r * 768 + c] * val;
            C[idx] = val;
        }
    }
}

// ---------------------------------------------------------------------------
// Weight precompute for folded cross-attention:
//   Mcat[i0, h*128+i] = sum_j Wq[i0, h*32+j] * Wk[i, h*32+j]
//   biasM[h*128+i]    = sum_j bq[h*32+j]    * Wk[i, h*32+j]
//   Pcat[h*128+i, j]  = sum_d Wv[i, h*32+d] * Wo[h*32+d, j]
//   co[j]             = bo[j] + sum_m bv[m] * Wo[m, j]
// (qh·bk is constant over l -> softmax invariant -> dropped)
// ---------------------------------------------------------------------------
__global__ __launch_bounds__(256) void prep_weights(
    const float* __restrict__ Wq, const float* __restrict__ bq,
    const float* __restrict__ Wk, const float* __restrict__ Wv,
    const float* __restrict__ bv, const float* __restrict__ Wo,
    const float* __restrict__ bo,
    float* __restrict__ Mcat, float* __restrict__ biasM,
    float* __restrict__ Pcat, float* __restrict__ co)
{
    int g = blockIdx.x * 256 + threadIdx.x;   // 0..65535
    {
        int i0 = g >> 9, col = g & 511, h = col >> 7, i = col & 127;
        float s = 0.f;
#pragma unroll 8
        for (int j = 0; j < 32; j++)
            s += Wq[i0 * 128 + h * 32 + j] * Wk[i * 128 + h * 32 + j];
        Mcat[g] = s;
    }
    {
        int rowp = g >> 7, j = g & 127, h = rowp >> 7, i = rowp & 127;
        float s = 0.f;
#pragma unroll 8
        for (int d = 0; d < 32; d++)
            s += Wv[i * 128 + h * 32 + d] * Wo[(h * 32 + d) * 128 + j];
        Pcat[g] = s;
    }
    if (g < 512) {
        int h = g >> 7, i = g & 127;
        float s = 0.f;
        for (int j = 0; j < 32; j++)
            s += bq[h * 32 + j] * Wk[i * 128 + h * 32 + j];
        biasM[g] = s;
    }
    if (g < 128) {
        float s = bo[g];
        for (int m = 0; m < 128; m++) s += bv[m] * Wo[m * 128 + g];
        co[g] = s;
    }
}

// ---------------------------------------------------------------------------
// LayerNorm + modulate / affine  (one node per 128-thread block)
// ---------------------------------------------------------------------------
__device__ __forceinline__ void ln_stats(float v, int t, float& mu, float& rs) {
    float s = v, ss = v * v;
#pragma unroll
    for (int m = 1; m < 64; m <<= 1) { s += __shfl_xor(s, m); ss += __shfl_xor(ss, m); }
    __shared__ float l_s[2], l_ss[2];
    int w = t >> 6;
    if ((t & 63) == 0) { l_s[w] = s; l_ss[w] = ss; }
    __syncthreads();
    float S = l_s[0] + l_s[1], SS = l_ss[0] + l_ss[1];
    mu = S * (1.f / 128.f);
    float var = SS * (1.f / 128.f) - mu * mu;
    rs = rsqrtf(var + 1e-6f);
}

__global__ __launch_bounds__(128) void ln_mod_kernel(
    const float* __restrict__ x, const float* __restrict__ mod,
    int shift_off, int scale_off, float* __restrict__ out)
{
    int node = blockIdx.x, t = threadIdx.x;
    float v = x[(size_t)node * 128 + t];
    float mu, rs;
    ln_stats(v, t, mu, rs);
    float xn = (v - mu) * rs;
    float shift = mod[(size_t)node * 768 + shift_off + t];
    float scale = mod[(size_t)node * 768 + scale_off + t];
    out[(size_t)node * 128 + t] = xn * (1.f + scale) + shift;
}

__global__ __launch_bounds__(128) void ln_affine_kernel(
    const float* __restrict__ x, const float* __restrict__ g,
    const float* __restrict__ b, float* __restrict__ out)
{
    int node = blockIdx.x, t = threadIdx.x;
    float v = x[(size_t)node * 128 + t];
    float mu, rs;
    ln_stats(v, t, mu, rs);
    out[(size_t)node * 128 + t] = (v - mu) * rs * g[t] + b[t];
}

// ---------------------------------------------------------------------------
// CSR build
// ---------------------------------------------------------------------------
__global__ void count_edges(const int* __restrict__ dst, int* __restrict__ count, int E) {
    int e = blockIdx.x * blockDim.x + threadIdx.x;
    if (e < E) atomicAdd(&count[dst[e]], 1);
}

__global__ __launch_bounds__(1024) void scan_kernel(
    const int* __restrict__ count, int* __restrict__ base,
    int* __restrict__ cursor, int n)
{
    __shared__ int tmp[1024];
    int tid = threadIdx.x;
    int carry = 0;
    if (tid == 0) base[0] = 0;
    for (int start = 0; start < n; start += 1024) {
        int idx = start + tid;
        int v = (idx < n) ? count[idx] : 0;
        tmp[tid] = v;
        __syncthreads();
        for (int off = 1; off < 1024; off <<= 1) {
            int add = (tid >= off) ? tmp[tid - off] : 0;
            __syncthreads();
            tmp[tid] += add;
            __syncthreads();
        }
        if (idx < n) {
            base[idx + 1] = carry + tmp[tid];
            cursor[idx] = carry + tmp[tid] - v;
        }
        carry += tmp[1023];
        __syncthreads();
    }
}

__global__ void scatter_edges(const int* __restrict__ src, const int* __restrict__ dst,
                              int* __restrict__ cursor, int* __restrict__ csr_src, int E) {
    int e = blockIdx.x * blockDim.x + threadIdx.x;
    if (e < E) {
        int pos = atomicAdd(&cursor[dst[e]], 1);
        csr_src[pos] = src[e];
    }
}

// ---------------------------------------------------------------------------
// Graph self-attention: one dst node per 128-thread block, online softmax over
// its incoming edges. Thread t: head h=t>>5, dims 4*(t&31)..+3
// x1 = x + gate_msa * (mean_h(agg) + sab)
// ---------------------------------------------------------------------------
__global__ __launch_bounds__(128) void sa_node_kernel(
    const float* __restrict__ q, const float* __restrict__ k, const float* __restrict__ v,
    const int* __restrict__ base, const int* __restrict__ csr_src,
    const float* __restrict__ x, const float* __restrict__ sab,
    const float* __restrict__ mod, float* __restrict__ x1)
{
    int node = blockIdx.x, t = threadIdx.x;
    float4 qv = *(const float4*)(q + (size_t)node * 512 + t * 4);
    int beg = base[node], end = base[node + 1];
    float m_run = -INFINITY, den = 0.f;
    float4 acc = make_float4(0.f, 0.f, 0.f, 0.f);
    for (int e = beg; e < end; e++) {
        int s = csr_src[e];
        float4 kv = *(const float4*)(k + (size_t)s * 512 + t * 4);
        float p = qv.x * kv.x + qv.y * kv.y + qv.z * kv.z + qv.w * kv.w;
#pragma unroll
        for (int mm = 1; mm < 32; mm <<= 1) p += __shfl_xor(p, mm);
        float logit = p * 0.08838834764831845f;  // 1/sqrt(128)
        float mn = fmaxf(m_run, logit);
        float corr = __expf(m_run - mn);
        float pe = __expf(logit - mn);
        float4 vv = *(const float4*)(v + (size_t)s * 512 + t * 4);
        acc.x = acc.x * corr + pe * vv.x;
        acc.y = acc.y * corr + pe * vv.y;
        acc.z = acc.z * corr + pe * vv.z;
        acc.w = acc.w * corr + pe * vv.w;
        den = den * corr + pe;
        m_run = mn;
    }
    float inv = (den > 0.f) ? 0.25f / den : 0.f;   // mean over 4 heads folded in
    __shared__ float red[512];
    *(float4*)&red[t * 4] = make_float4(acc.x * inv, acc.y * inv, acc.z * inv, acc.w * inv);
    __syncthreads();
    float sa = red[t] + red[128 + t] + red[256 + t] + red[384 + t];
    float g = mod[(size_t)node * 768 + 256 + t];
    size_t idx = (size_t)node * 128 + t;
    x1[idx] = x[idx] + g * (sa + sab[idx]);
}

// ---------------------------------------------------------------------------
// Cross-attention middle: per node, scores = (te @ qw^T)/sqrt(32), softmax over
// L=32, u[h,:] = attn[h,:] @ te.   te:[32,128] staged in LDS.
// ---------------------------------------------------------------------------
__global__ __launch_bounds__(128) void cross_mid_kernel(
    const float* __restrict__ te, const float* __restrict__ qw,
    float* __restrict__ u)
{
    int node = blockIdx.x, t = threadIdx.x;
    __shared__ float tes[32 * 132];
    __shared__ float qws[512];
    __shared__ float attnL[128];
#pragma unroll
    for (int i = 0; i < 8; i++) {
        int f = t + i * 128;                 // 0..1023 float4 slots
        int l = f >> 5, ii = (f & 31) * 4;
        float4 val = *(const float4*)(te + (size_t)node * 4096 + l * 128 + ii);
        *(float4*)&tes[l * 132 + ii] = val;
    }
    *(float4*)&qws[t * 4] = *(const float4*)(qw + (size_t)node * 512 + t * 4);
    __syncthreads();

    int h = t >> 5, l = t & 31;
    float sc = 0.f;
#pragma unroll 8
    for (int i = 0; i < 128; i++) sc += tes[l * 132 + i] * qws[h * 128 + i];
    sc *= 0.17677669529663687f;  // 1/sqrt(32)
    float mx = sc;
#pragma unroll
    for (int mm = 1; mm < 32; mm <<= 1) mx = fmaxf(mx, __shfl_xor(mx, mm));
    float e = __expf(sc - mx);
    float ssum = e;
#pragma unroll
    for (int mm = 1; mm < 32; mm <<= 1) ssum += __shfl_xor(ssum, mm);
    attnL[t] = e / ssum;
    __syncthreads();

    int i0 = t & 31;
    float u0 = 0, u1 = 0, u2 = 0, u3 = 0;
#pragma unroll 4
    for (int ll = 0; ll < 32; ll++) {
        float a = attnL[h * 32 + ll];
        u0 += a * tes[ll * 132 + i0];
        u1 += a * tes[ll * 132 + i0 + 32];
        u2 += a * tes[ll * 132 + i0 + 64];
        u3 += a * tes[ll * 132 + i0 + 96];
    }
    size_t ub = (size_t)node * 512 + h * 128;
    u[ub + i0] = u0; u[ub + i0 + 32] = u1; u[ub + i0 + 64] = u2; u[ub + i0 + 96] = u3;
}

// ---------------------------------------------------------------------------
extern "C" void kernel_launch(void* const* d_in, const int* in_sizes, int n_in,
                              void* d_out, int out_size, void* d_ws, size_t ws_size,
                              hipStream_t stream)
{
    const int N = in_sizes[0] / 128;        // 20000
    const int E = in_sizes[1] / 2;          // 320000

    const float* x      = (const float*)d_in[0];
    const int*   ei     = (const int*)d_in[1];     // [2,E]: src=ei, dst=ei+E
    const float* t_in   = (const float*)d_in[2];
    const float* te     = (const float*)d_in[3];
    const float* sa_q_w = (const float*)d_in[4];
    const float* sa_q_b = (const float*)d_in[5];
    const float* sa_k_w = (const float*)d_in[6];
    const float* sa_k_b = (const float*)d_in[7];
    const float* sa_v_w = (const float*)d_in[8];
    const float* sa_v_b = (const float*)d_in[9];
    const float* sa_skip_w = (const float*)d_in[10];
    const float* sa_skip_b = (const float*)d_in[11];
    const float* n3_g   = (const float*)d_in[12];
    const float* n3_b   = (const float*)d_in[13];
    const float* mha_q_w = (const float*)d_in[14];
    const float* mha_q_b = (const float*)d_in[15];
    const float* mha_k_w = (const float*)d_in[16];
    // mha_k_b (d_in[17]) is softmax-invariant -> unused
    const float* mha_v_w = (const float*)d_in[18];
    const float* mha_v_b = (const float*)d_in[19];
    const float* mha_o_w = (const float*)d_in[20];
    const float* mha_o_b = (const float*)d_in[21];
    const float* fc1_w  = (const float*)d_in[22];
    const float* fc1_b  = (const float*)d_in[23];
    const float* fc2_w  = (const float*)d_in[24];
    const float* fc2_b  = (const float*)d_in[25];
    const float* ada_w  = (const float*)d_in[26];
    const float* ada_b  = (const float*)d_in[27];
    float* out = (float*)d_out;

    // workspace layout (floats), aliased across stages
    float* ws = (float*)d_ws;
    size_t o = 0;
    float* modb = ws + o; o += (size_t)N * 768;   // mod (all 6 chunks, live whole call)
    float* Bbuf = ws + o; o += (size_t)N * 128;   // xm -> qn -> xm2
    float* Cbuf = ws + o; o += (size_t)N * 512;   // q -> qw
    float* Dbuf = ws + o; o += (size_t)N * 512;   // k -> u
    float* Ebuf = ws + o; o += (size_t)N * 512;   // v -> h
    float* Fbuf = ws + o; o += (size_t)N * 128;   // sab
    float* Gbuf = ws + o; o += (size_t)N * 128;   // x1 -> x2 (in-place)
    float* Mcat = ws + o; o += 128 * 512;
    float* Pcat = ws + o; o += 512 * 128;
    float* biasM = ws + o; o += 512;
    float* co   = ws + o; o += 128;
    int* count   = (int*)(ws + o); o += N;
    int* base    = (int*)(ws + o); o += N + 1;
    int* cursor  = (int*)(ws + o); o += N;
    int* csr_src = (int*)(ws + o); o += E;

    const int* src = ei;
    const int* dst = ei + E;
    const int rowBlocks = (N + GBM - 1) / GBM;

    // folded cross-attn weights
    prep_weights<<<256, 256, 0, stream>>>(mha_q_w, mha_q_b, mha_k_w, mha_v_w,
                                          mha_v_b, mha_o_w, mha_o_b,
                                          Mcat, biasM, Pcat, co);
    // CSR build
    hipMemsetAsync(count, 0, (size_t)N * sizeof(int), stream);
    count_edges<<<(E + 255) / 256, 256, 0, stream>>>(dst, count, E);
    scan_kernel<<<1, 1024, 0, stream>>>(count, base, cursor, N);
    scatter_edges<<<(E + 255) / 256, 256, 0, stream>>>(src, dst, cursor, csr_src, E);

    // adaLN: mod = silu(t) @ ada_w + ada_b
    gemm_kernel<1, 0><<<dim3(rowBlocks, 768 / GBN), 256, 0, stream>>>(
        t_in, ada_w, ada_b, modb, nullptr, nullptr, N, 128, 768);

    // xm = modulate(ln(x), shift_msa, scale_msa)
    ln_mod_kernel<<<N, 128, 0, stream>>>(x, modb, 0, 128, Bbuf);

    // q,k,v, skip
    gemm_kernel<0, 0><<<dim3(rowBlocks, 512 / GBN), 256, 0, stream>>>(
        Bbuf, sa_q_w, sa_q_b, Cbuf, nullptr, nullptr, N, 128, 512);
    gemm_kernel<0, 0><<<dim3(rowBlocks, 512 / GBN), 256, 0, stream>>>(
        Bbuf, sa_k_w, sa_k_b, Dbuf, nullptr, nullptr, N, 128, 512);
    gemm_kernel<0, 0><<<dim3(rowBlocks, 512 / GBN), 256, 0, stream>>>(
        Bbuf, sa_v_w, sa_v_b, Ebuf, nullptr, nullptr, N, 128, 512);
    gemm_kernel<0, 0><<<dim3(rowBlocks, 128 / GBN), 256, 0, stream>>>(
        Bbuf, sa_skip_w, sa_skip_b, Fbuf, nullptr, nullptr, N, 128, 128);

    // graph attention + residual -> x1 (Gbuf)
    sa_node_kernel<<<N, 128, 0, stream>>>(Cbuf, Dbuf, Ebuf, base, csr_src,
                                          x, Fbuf, modb, Gbuf);

    // cross attention (folded): qn -> qw -> mid -> out GEMM (in-place residual)
    ln_affine_kernel<<<N, 128, 0, stream>>>(Gbuf, n3_g, n3_b, Bbuf);
    gemm_kernel<0, 0><<<dim3(rowBlocks, 512 / GBN), 256, 0, stream>>>(
        Bbuf, Mcat, biasM, Cbuf, nullptr, nullptr, N, 128, 512);
    cross_mid_kernel<<<N, 128, 0, stream>>>(te, Cbuf, Dbuf);
    gemm_kernel<0, 2><<<dim3(rowBlocks, 128 / GBN), 256, 0, stream>>>(
        Dbuf, Pcat, co, Gbuf, Gbuf, nullptr, N, 512, 128);   // x2 = x1 + u@Pcat + co

    // MLP
    ln_mod_kernel<<<N, 128, 0, stream>>>(Gbuf, modb, 384, 512, Bbuf);
    gemm_kernel<0, 1><<<dim3(rowBlocks, 512 / GBN), 256, 0, stream>>>(
        Bbuf, fc1_w, fc1_b, Ebuf, nullptr, nullptr, N, 128, 512);
    gemm_kernel<0, 3><<<dim3(rowBlocks, 128 / GBN), 256, 0, stream>>>(
        Ebuf, fc2_w, fc2_b, out, Gbuf, modb + 640, N, 512, 128);
}

// Round 2
// 513.416 us; speedup vs baseline: 2.1023x; 2.1023x over previous
//
#include <hip/hip_runtime.h>
#include <hip/hip_bf16.h>
#include <math.h>

using ushort8 = __attribute__((ext_vector_type(8))) unsigned short;
using short8  = __attribute__((ext_vector_type(8))) short;
using f32x4   = __attribute__((ext_vector_type(4))) float;

__device__ __forceinline__ float bf2f(unsigned short u) {
    union { unsigned int i; float f; } c; c.i = ((unsigned int)u) << 16; return c.f;
}
__device__ __forceinline__ unsigned short f2bf(float f) {
    __hip_bfloat16 h = __float2bfloat16(f);
    return *reinterpret_cast<unsigned short*>(&h);
}
__device__ __forceinline__ float silu_f(float x) { return x / (1.f + __expf(-x)); }
__device__ __forceinline__ float gelu_f(float x) {
    float x3 = x * x * x;
    return 0.5f * x * (1.f + tanhf(0.7978845608028654f * (x + 0.044715f * x3)));
}

// ---------------------------------------------------------------------------
// bf16 MFMA GEMM: C = epi(pre(A_f32) @ Wt_bf16^T + bias)
// A: [N,K] f32 row-major. Wt: [M,K] bf16 row-major (pre-transposed weights).
// Tile BM=128, BN=128, BK=64. 256 threads = 4 waves (2x2), wave tile 64x64.
// PRE: 0=none 1=silu   EPI: 0=none 1=gelu 2=res+val 3=res+gate*val
// OUTBF: 0=f32 out, 1=bf16 out
// ---------------------------------------------------------------------------
template<int PRE, int EPI, int OUTBF>
__global__ __launch_bounds__(256) void gemm_mfma(
    const float* __restrict__ A, const unsigned short* __restrict__ Wt,
    const float* __restrict__ bias, void* __restrict__ Cout,
    const float* __restrict__ res, const float* __restrict__ gate,
    int Nrows, int K, int M)
{
    __shared__ unsigned short As[128][64];
    __shared__ unsigned short Bs[128][64];
    const int tid = threadIdx.x;
    const int row0 = blockIdx.x * 128;
    const int col0 = blockIdx.y * 128;
    const int lane = tid & 63;
    const int wid  = tid >> 6;
    const int wr = (wid >> 1) * 64;
    const int wc = (wid & 1) * 64;
    const int lr = lane & 15;
    const int lk = lane >> 4;          // 0..3

    f32x4 acc[4][4];
#pragma unroll
    for (int i = 0; i < 4; i++)
#pragma unroll
        for (int j = 0; j < 4; j++) acc[i][j] = (f32x4)0.f;

    for (int k0 = 0; k0 < K; k0 += 64) {
        // stage A (f32 -> bf16, XOR-swizzled 16B blocks)
#pragma unroll
        for (int i = 0; i < 4; i++) {
            int f = tid + i * 256;            // 0..1023
            int m = f >> 3, b = f & 7;
            int r = row0 + m;
            float v[8];
            if (r < Nrows) {
                const float* ap = A + (size_t)r * K + k0 + b * 8;
                float4 p0 = *(const float4*)ap;
                float4 p1 = *(const float4*)(ap + 4);
                v[0]=p0.x; v[1]=p0.y; v[2]=p0.z; v[3]=p0.w;
                v[4]=p1.x; v[5]=p1.y; v[6]=p1.z; v[7]=p1.w;
                if (PRE == 1) {
#pragma unroll
                    for (int j = 0; j < 8; j++) v[j] = silu_f(v[j]);
                }
            } else {
#pragma unroll
                for (int j = 0; j < 8; j++) v[j] = 0.f;
            }
            ushort8 h;
#pragma unroll
            for (int j = 0; j < 8; j++) h[j] = f2bf(v[j]);
            *(ushort8*)&As[m][((b ^ (m & 7))) * 8] = h;
        }
        // stage B (already bf16 [M,K])
#pragma unroll
        for (int i = 0; i < 4; i++) {
            int f = tid + i * 256;
            int n = f >> 3, b = f & 7;
            ushort8 w = *(const ushort8*)(Wt + (size_t)(col0 + n) * K + k0 + b * 8);
            *(ushort8*)&Bs[n][((b ^ (n & 7))) * 8] = w;
        }
        __syncthreads();

        short8 afr[4][2], bfr[4][2];
#pragma unroll
        for (int fr = 0; fr < 4; fr++)
#pragma unroll
            for (int s = 0; s < 2; s++) {
                int m = wr + fr * 16 + lr;
                int blk = (s * 4 + lk) ^ (m & 7);
                afr[fr][s] = *(const short8*)&As[m][blk * 8];
            }
#pragma unroll
        for (int fc = 0; fc < 4; fc++)
#pragma unroll
            for (int s = 0; s < 2; s++) {
                int n = wc + fc * 16 + lr;
                int blk = (s * 4 + lk) ^ (n & 7);
                bfr[fc][s] = *(const short8*)&Bs[n][blk * 8];
            }
#pragma unroll
        for (int fr = 0; fr < 4; fr++)
#pragma unroll
            for (int fc = 0; fc < 4; fc++)
#pragma unroll
                for (int s = 0; s < 2; s++)
                    acc[fr][fc] = __builtin_amdgcn_mfma_f32_16x16x32_bf16(
                        afr[fr][s], bfr[fc][s], acc[fr][fc], 0, 0, 0);
        __syncthreads();
    }

    // epilogue: D row=(lane>>4)*4+r, col=lane&15 within each 16x16 frag
#pragma unroll
    for (int fr = 0; fr < 4; fr++) {
#pragma unroll
        for (int fc = 0; fc < 4; fc++) {
#pragma unroll
            for (int r = 0; r < 4; r++) {
                int row = row0 + wr + fr * 16 + (lane >> 4) * 4 + r;
                if (row >= Nrows) continue;
                int col = col0 + wc + fc * 16 + (lane & 15);
                float val = acc[fr][fc][r] + bias[col];
                size_t idx = (size_t)row * M + col;
                if (EPI == 1) val = gelu_f(val);
                else if (EPI == 2) val = res[idx] + val;
                else if (EPI == 3) val = res[idx] + gate[(size_t)row * 768 + col] * val;
                if (OUTBF) ((unsigned short*)Cout)[idx] = f2bf(val);
                else       ((float*)Cout)[idx] = val;
            }
        }
    }
}

// ---------------------------------------------------------------------------
// Weight transpose+convert: Wt[m*K+k] = bf16(W[k*M+m]); optional bias copy
// ---------------------------------------------------------------------------
__global__ void conv_wt(const float* __restrict__ W, const float* __restrict__ b,
                        int K, int M, unsigned short* __restrict__ Wt,
                        float* __restrict__ bias_out)
{
    int g = blockIdx.x * 256 + threadIdx.x;
    if (g < M * K) {
        int m = g / K, k = g - m * K;
        Wt[g] = f2bf(W[(size_t)k * M + m]);
    }
    if (bias_out && g < M) bias_out[g] = b[g];
}

// ---------------------------------------------------------------------------
// Folded cross-attention weights (bf16, pre-transposed [M,K]):
//   Mcat_t[col, i0] = sum_j Wq[i0, h*32+j] * Wk[i, h*32+j]   (col=h*128+i)
//   biasM[h*128+i]  = sum_j bq[h*32+j]    * Wk[i, h*32+j]
//   Pcat_t[j, rowp] = sum_d Wv[i, h*32+d] * Wo[h*32+d, j]    (rowp=h*128+i)
//   co[j]           = bo[j] + sum_m bv[m] * Wo[m, j]
// ---------------------------------------------------------------------------
__global__ __launch_bounds__(256) void prep_weights(
    const float* __restrict__ Wq, const float* __restrict__ bq,
    const float* __restrict__ Wk, const float* __restrict__ Wv,
    const float* __restrict__ bv, const float* __restrict__ Wo,
    const float* __restrict__ bo,
    unsigned short* __restrict__ Mcat_t, float* __restrict__ biasM,
    unsigned short* __restrict__ Pcat_t, float* __restrict__ co)
{
    int g = blockIdx.x * 256 + threadIdx.x;   // 0..65535
    {
        int i0 = g >> 9, col = g & 511, h = col >> 7, i = col & 127;
        float s = 0.f;
#pragma unroll 8
        for (int j = 0; j < 32; j++)
            s += Wq[i0 * 128 + h * 32 + j] * Wk[i * 128 + h * 32 + j];
        Mcat_t[col * 128 + i0] = f2bf(s);
    }
    {
        int rowp = g >> 7, j = g & 127, h = rowp >> 7, i = rowp & 127;
        float s = 0.f;
#pragma unroll 8
        for (int d = 0; d < 32; d++)
            s += Wv[i * 128 + h * 32 + d] * Wo[(h * 32 + d) * 128 + j];
        Pcat_t[j * 512 + rowp] = f2bf(s);
    }
    if (g < 512) {
        int h = g >> 7, i = g & 127;
        float s = 0.f;
        for (int j = 0; j < 32; j++)
            s += bq[h * 32 + j] * Wk[i * 128 + h * 32 + j];
        biasM[g] = s;
    }
    if (g < 128) {
        float s = bo[g];
        for (int m = 0; m < 128; m++) s += bv[m] * Wo[m * 128 + g];
        co[g] = s;
    }
}

// ---------------------------------------------------------------------------
// LayerNorm + modulate / affine  (one node per 128-thread block)
// ---------------------------------------------------------------------------
__device__ __forceinline__ void ln_stats(float v, int t, float& mu, float& rs) {
    float s = v, ss = v * v;
#pragma unroll
    for (int m = 1; m < 64; m <<= 1) { s += __shfl_xor(s, m); ss += __shfl_xor(ss, m); }
    __shared__ float l_s[2], l_ss[2];
    int w = t >> 6;
    if ((t & 63) == 0) { l_s[w] = s; l_ss[w] = ss; }
    __syncthreads();
    float S = l_s[0] + l_s[1], SS = l_ss[0] + l_ss[1];
    mu = S * (1.f / 128.f);
    float var = SS * (1.f / 128.f) - mu * mu;
    rs = rsqrtf(var + 1e-6f);
}

__global__ __launch_bounds__(128) void ln_mod_kernel(
    const float* __restrict__ x, const float* __restrict__ mod,
    int shift_off, int scale_off, float* __restrict__ out)
{
    int node = blockIdx.x, t = threadIdx.x;
    float v = x[(size_t)node * 128 + t];
    float mu, rs;
    ln_stats(v, t, mu, rs);
    float xn = (v - mu) * rs;
    float shift = mod[(size_t)node * 768 + shift_off + t];
    float scale = mod[(size_t)node * 768 + scale_off + t];
    out[(size_t)node * 128 + t] = xn * (1.f + scale) + shift;
}

__global__ __launch_bounds__(128) void ln_affine_kernel(
    const float* __restrict__ x, const float* __restrict__ g,
    const float* __restrict__ b, float* __restrict__ out)
{
    int node = blockIdx.x, t = threadIdx.x;
    float v = x[(size_t)node * 128 + t];
    float mu, rs;
    ln_stats(v, t, mu, rs);
    out[(size_t)node * 128 + t] = (v - mu) * rs * g[t] + b[t];
}

// ---------------------------------------------------------------------------
// CSR build: count -> 2-level scan -> scatter
// ---------------------------------------------------------------------------
__global__ void count_edges(const int* __restrict__ dst, int* __restrict__ count, int E) {
    int e = blockIdx.x * blockDim.x + threadIdx.x;
    if (e < E) atomicAdd(&count[dst[e]], 1);
}

__global__ __launch_bounds__(1024) void scan_block(const int* __restrict__ cnt,
                                                   int* __restrict__ pre,
                                                   int* __restrict__ bsum, int n)
{
    __shared__ int tmp[1024];
    int gid = blockIdx.x * 1024 + threadIdx.x;
    int v = (gid < n) ? cnt[gid] : 0;
    tmp[threadIdx.x] = v;
    __syncthreads();
    for (int off = 1; off < 1024; off <<= 1) {
        int add = (threadIdx.x >= off) ? tmp[threadIdx.x - off] : 0;
        __syncthreads();
        tmp[threadIdx.x] += add;
        __syncthreads();
    }
    if (gid < n) pre[gid] = tmp[threadIdx.x];
    if (threadIdx.x == 1023) bsum[blockIdx.x] = tmp[1023];
}

__global__ void scan_tops(int* __restrict__ bsum, int nb) {
    if (threadIdx.x == 0 && blockIdx.x == 0) {
        int c = 0;
        for (int i = 0; i < nb; i++) { int v = bsum[i]; bsum[i] = c; c += v; }
    }
}

__global__ void scan_fix(const int* __restrict__ pre, const int* __restrict__ bsum,
                         const int* __restrict__ cnt,
                         int* __restrict__ base, int* __restrict__ cursor, int n)
{
    int gid = blockIdx.x * 256 + threadIdx.x;
    if (gid < n) {
        int inc = pre[gid] + bsum[gid >> 10];
        base[gid + 1] = inc;
        cursor[gid] = inc - cnt[gid];
    }
    if (gid == 0) base[0] = 0;
}

__global__ void scatter_edges(const int* __restrict__ src, const int* __restrict__ dst,
                              int* __restrict__ cursor, int* __restrict__ csr_src, int E) {
    int e = blockIdx.x * blockDim.x + threadIdx.x;
    if (e < E) {
        int pos = atomicAdd(&cursor[dst[e]], 1);
        csr_src[pos] = src[e];
    }
}

// ---------------------------------------------------------------------------
// Graph self-attention over bf16 qkv buffer [N,1664]: q 0..511, k 512..1023,
// v 1024..1535, skip 1536..1663. One dst node per 128-thread block.
// ---------------------------------------------------------------------------
__global__ __launch_bounds__(128) void sa_node_kernel(
    const unsigned short* __restrict__ qkv,
    const int* __restrict__ base, const int* __restrict__ csr_src,
    const float* __restrict__ x, const float* __restrict__ mod,
    float* __restrict__ x1)
{
    int node = blockIdx.x, t = threadIdx.x;
    const size_t nb = (size_t)node * 1664;
    ushort4 qu = *(const ushort4*)(qkv + nb + t * 4);
    const float sc = 0.08838834764831845f;   // 1/sqrt(128)
    float q0 = bf2f(qu.x) * sc, q1 = bf2f(qu.y) * sc;
    float q2 = bf2f(qu.z) * sc, q3 = bf2f(qu.w) * sc;
    int beg = base[node], end = base[node + 1];
    float m_run = -INFINITY, den = 0.f;
    float a0 = 0.f, a1 = 0.f, a2 = 0.f, a3 = 0.f;
    ushort4 kc, vc;
    kc.x = kc.y = kc.z = kc.w = 0;
    vc = kc;
    if (beg < end) {
        int s = csr_src[beg];
        const unsigned short* kp = qkv + (size_t)s * 1664 + 512 + t * 4;
        kc = *(const ushort4*)kp;
        vc = *(const ushort4*)(kp + 512);
    }
    for (int e = beg; e < end; e++) {
        ushort4 kn = kc, vn = vc;
        if (e + 1 < end) {
            int s1 = csr_src[e + 1];
            const unsigned short* kp = qkv + (size_t)s1 * 1664 + 512 + t * 4;
            kn = *(const ushort4*)kp;
            vn = *(const ushort4*)(kp + 512);
        }
        float p = q0 * bf2f(kc.x) + q1 * bf2f(kc.y) + q2 * bf2f(kc.z) + q3 * bf2f(kc.w);
#pragma unroll
        for (int mm = 1; mm < 32; mm <<= 1) p += __shfl_xor(p, mm);
        float mn = fmaxf(m_run, p);
        float corr = __expf(m_run - mn);
        float pe = __expf(p - mn);
        a0 = a0 * corr + pe * bf2f(vc.x);
        a1 = a1 * corr + pe * bf2f(vc.y);
        a2 = a2 * corr + pe * bf2f(vc.z);
        a3 = a3 * corr + pe * bf2f(vc.w);
        den = den * corr + pe;
        m_run = mn;
        kc = kn; vc = vn;
    }
    float inv = (den > 0.f) ? 0.25f / den : 0.f;   // mean over 4 heads folded in
    __shared__ float red[512];
    *(float4*)&red[t * 4] = make_float4(a0 * inv, a1 * inv, a2 * inv, a3 * inv);
    __syncthreads();
    float sa = red[t] + red[128 + t] + red[256 + t] + red[384 + t];
    float sab = bf2f(qkv[nb + 1536 + t]);
    float g = mod[(size_t)node * 768 + 256 + t];
    size_t idx = (size_t)node * 128 + t;
    x1[idx] = x[idx] + g * (sa + sab);
}

// ---------------------------------------------------------------------------
// Cross-attention middle: scores = (te @ qw^T)/sqrt(32), softmax over L=32,
// u[h,:] = attn[h,:] @ te.   te:[32,128] staged in LDS.
// ---------------------------------------------------------------------------
__global__ __launch_bounds__(128) void cross_mid_kernel(
    const float* __restrict__ te, const float* __restrict__ qw,
    float* __restrict__ u)
{
    int node = blockIdx.x, t = threadIdx.x;
    __shared__ float tes[32 * 132];
    __shared__ float qws[512];
    __shared__ float attnL[128];
#pragma unroll
    for (int i = 0; i < 8; i++) {
        int f = t + i * 128;
        int l = f >> 5, ii = (f & 31) * 4;
        float4 val = *(const float4*)(te + (size_t)node * 4096 + l * 128 + ii);
        *(float4*)&tes[l * 132 + ii] = val;
    }
    *(float4*)&qws[t * 4] = *(const float4*)(qw + (size_t)node * 512 + t * 4);
    __syncthreads();

    int h = t >> 5, l = t & 31;
    float sc = 0.f;
#pragma unroll 8
    for (int i = 0; i < 128; i++) sc += tes[l * 132 + i] * qws[h * 128 + i];
    sc *= 0.17677669529663687f;  // 1/sqrt(32)
    float mx = sc;
#pragma unroll
    for (int mm = 1; mm < 32; mm <<= 1) mx = fmaxf(mx, __shfl_xor(mx, mm));
    float e = __expf(sc - mx);
    float ssum = e;
#pragma unroll
    for (int mm = 1; mm < 32; mm <<= 1) ssum += __shfl_xor(ssum, mm);
    attnL[t] = e / ssum;
    __syncthreads();

    int i0 = t & 31;
    float u0 = 0, u1 = 0, u2 = 0, u3 = 0;
#pragma unroll 4
    for (int ll = 0; ll < 32; ll++) {
        float a = attnL[h * 32 + ll];
        u0 += a * tes[ll * 132 + i0];
        u1 += a * tes[ll * 132 + i0 + 32];
        u2 += a * tes[ll * 132 + i0 + 64];
        u3 += a * tes[ll * 132 + i0 + 96];
    }
    size_t ub = (size_t)node * 512 + h * 128;
    u[ub + i0] = u0; u[ub + i0 + 32] = u1; u[ub + i0 + 64] = u2; u[ub + i0 + 96] = u3;
}

// ---------------------------------------------------------------------------
extern "C" void kernel_launch(void* const* d_in, const int* in_sizes, int n_in,
                              void* d_out, int out_size, void* d_ws, size_t ws_size,
                              hipStream_t stream)
{
    const int N = in_sizes[0] / 128;        // 20000
    const int E = in_sizes[1] / 2;          // 320000

    const float* x      = (const float*)d_in[0];
    const int*   ei     = (const int*)d_in[1];
    const float* t_in   = (const float*)d_in[2];
    const float* te     = (const float*)d_in[3];
    const float* sa_q_w = (const float*)d_in[4];
    const float* sa_q_b = (const float*)d_in[5];
    const float* sa_k_w = (const float*)d_in[6];
    const float* sa_k_b = (const float*)d_in[7];
    const float* sa_v_w = (const float*)d_in[8];
    const float* sa_v_b = (const float*)d_in[9];
    const float* sa_skip_w = (const float*)d_in[10];
    const float* sa_skip_b = (const float*)d_in[11];
    const float* n3_g   = (const float*)d_in[12];
    const float* n3_b   = (const float*)d_in[13];
    const float* mha_q_w = (const float*)d_in[14];
    const float* mha_q_b = (const float*)d_in[15];
    const float* mha_k_w = (const float*)d_in[16];
    const float* mha_v_w = (const float*)d_in[18];
    const float* mha_v_b = (const float*)d_in[19];
    const float* mha_o_w = (const float*)d_in[20];
    const float* mha_o_b = (const float*)d_in[21];
    const float* fc1_w  = (const float*)d_in[22];
    const float* fc1_b  = (const float*)d_in[23];
    const float* fc2_w  = (const float*)d_in[24];
    const float* fc2_b  = (const float*)d_in[25];
    const float* ada_w  = (const float*)d_in[26];
    const float* ada_b  = (const float*)d_in[27];
    float* out = (float*)d_out;

    // workspace layout (float units, all 16B-aligned)
    float* ws = (float*)d_ws;
    size_t o = 0;
    float* modb = ws + o; o += (size_t)N * 768;
    float* Bbuf = ws + o; o += (size_t)N * 128;   // xm -> qn -> xm2
    float* Cbuf = ws + o; o += (size_t)N * 512;   // qw
    float* Dbuf = ws + o; o += (size_t)N * 512;   // u
    float* Ebuf = ws + o; o += (size_t)N * 512;   // h
    float* Gbuf = ws + o; o += (size_t)N * 128;   // x1 -> x2
    unsigned short* QKV = (unsigned short*)(ws + o); o += (size_t)N * 832;  // [N,1664] bf16
    unsigned short* Wsa_t  = (unsigned short*)(ws + o); o += 1664 * 128 / 2;
    unsigned short* Mcat_t = (unsigned short*)(ws + o); o += 512 * 128 / 2;
    unsigned short* Pcat_t = (unsigned short*)(ws + o); o += 128 * 512 / 2;
    unsigned short* fc1_t  = (unsigned short*)(ws + o); o += 512 * 128 / 2;
    unsigned short* fc2_t  = (unsigned short*)(ws + o); o += 128 * 512 / 2;
    unsigned short* ada_t  = (unsigned short*)(ws + o); o += 768 * 128 / 2;
    float* bsa   = ws + o; o += 1664;
    float* biasM = ws + o; o += 512;
    float* co    = ws + o; o += 128;
    int* count   = (int*)(ws + o); o += N;
    int* base    = (int*)(ws + o); o += N + 4;
    int* cursor  = (int*)(ws + o); o += N;
    int* pre     = (int*)(ws + o); o += N;
    int* bsum    = (int*)(ws + o); o += 32;
    int* csr_src = (int*)(ws + o); o += E;

    const int* src = ei;
    const int* dst = ei + E;
    const int rowBlocks = (N + 127) / 128;
    const int nScan = (N + 1023) / 1024;

    // ---- weight prep (bf16, transposed) ----
    prep_weights<<<256, 256, 0, stream>>>(mha_q_w, mha_q_b, mha_k_w, mha_v_w,
                                          mha_v_b, mha_o_w, mha_o_b,
                                          Mcat_t, biasM, Pcat_t, co);
    conv_wt<<<256, 256, 0, stream>>>(sa_q_w, sa_q_b, 128, 512, Wsa_t, bsa);
    conv_wt<<<256, 256, 0, stream>>>(sa_k_w, sa_k_b, 128, 512, Wsa_t + 512 * 128, bsa + 512);
    conv_wt<<<256, 256, 0, stream>>>(sa_v_w, sa_v_b, 128, 512, Wsa_t + 1024 * 128, bsa + 1024);
    conv_wt<<<64, 256, 0, stream>>>(sa_skip_w, sa_skip_b, 128, 128, Wsa_t + 1536 * 128, bsa + 1536);
    conv_wt<<<256, 256, 0, stream>>>(fc1_w, fc1_b, 128, 512, fc1_t, nullptr);
    conv_wt<<<256, 256, 0, stream>>>(fc2_w, fc2_b, 512, 128, fc2_t, nullptr);
    conv_wt<<<384, 256, 0, stream>>>(ada_w, ada_b, 128, 768, ada_t, nullptr);

    // ---- CSR build ----
    hipMemsetAsync(count, 0, (size_t)N * sizeof(int), stream);
    count_edges<<<(E + 255) / 256, 256, 0, stream>>>(dst, count, E);
    scan_block<<<nScan, 1024, 0, stream>>>(count, pre, bsum, N);
    scan_tops<<<1, 64, 0, stream>>>(bsum, nScan);
    scan_fix<<<(N + 255) / 256, 256, 0, stream>>>(pre, bsum, count, base, cursor, N);
    scatter_edges<<<(E + 255) / 256, 256, 0, stream>>>(src, dst, cursor, csr_src, E);

    // ---- adaLN: mod = silu(t) @ ada_w + ada_b ----
    gemm_mfma<1, 0, 0><<<dim3(rowBlocks, 6), 256, 0, stream>>>(
        t_in, ada_t, ada_b, modb, nullptr, nullptr, N, 128, 768);

    // ---- xm = modulate(ln(x), shift_msa, scale_msa) ----
    ln_mod_kernel<<<N, 128, 0, stream>>>(x, modb, 0, 128, Bbuf);

    // ---- fused q|k|v|skip GEMM -> bf16 [N,1664] ----
    gemm_mfma<0, 0, 1><<<dim3(rowBlocks, 13), 256, 0, stream>>>(
        Bbuf, Wsa_t, bsa, QKV, nullptr, nullptr, N, 128, 1664);

    // ---- graph attention + residual -> x1 (Gbuf) ----
    sa_node_kernel<<<N, 128, 0, stream>>>(QKV, base, csr_src, x, modb, Gbuf);

    // ---- cross attention (folded) ----
    ln_affine_kernel<<<N, 128, 0, stream>>>(Gbuf, n3_g, n3_b, Bbuf);
    gemm_mfma<0, 0, 0><<<dim3(rowBlocks, 4), 256, 0, stream>>>(
        Bbuf, Mcat_t, biasM, Cbuf, nullptr, nullptr, N, 128, 512);
    cross_mid_kernel<<<N, 128, 0, stream>>>(te, Cbuf, Dbuf);
    gemm_mfma<0, 2, 0><<<dim3(rowBlocks, 1), 256, 0, stream>>>(
        Dbuf, Pcat_t, co, Gbuf, Gbuf, nullptr, N, 512, 128);   // x2 = x1 + u@Pcat + co

    // ---- MLP ----
    ln_mod_kernel<<<N, 128, 0, stream>>>(Gbuf, modb, 384, 512, Bbuf);
    gemm_mfma<0, 1, 0><<<dim3(rowBlocks, 4), 256, 0, stream>>>(
        Bbuf, fc1_t, fc1_b, Ebuf, nullptr, nullptr, N, 128, 512);
    gemm_mfma<0, 3, 0><<<dim3(rowBlocks, 1), 256, 0, stream>>>(
        Ebuf, fc2_t, fc2_b, out, Gbuf, modb + 640, N, 512, 128);
}

// Round 3
// 449.827 us; speedup vs baseline: 2.3995x; 1.1414x over previous
//
#include <hip/hip_runtime.h>
#include <hip/hip_bf16.h>
#include <math.h>

using ushort8 = __attribute__((ext_vector_type(8))) unsigned short;
using short8  = __attribute__((ext_vector_type(8))) short;
using f32x4   = __attribute__((ext_vector_type(4))) float;

__device__ __forceinline__ float bf2f(unsigned short u) {
    union { unsigned int i; float f; } c; c.i = ((unsigned int)u) << 16; return c.f;
}
__device__ __forceinline__ unsigned short f2bf(float f) {
    __hip_bfloat16 h = __float2bfloat16(f);
    return *reinterpret_cast<unsigned short*>(&h);
}
__device__ __forceinline__ float silu_f(float x) { return x / (1.f + __expf(-x)); }
__device__ __forceinline__ float gelu_f(float x) {
    float x3 = x * x * x;
    return 0.5f * x * (1.f + tanhf(0.7978845608028654f * (x + 0.044715f * x3)));
}

// ---------------------------------------------------------------------------
// bf16 MFMA GEMM: C = epi(pre(A) @ Wt^T + bias)
// A: [N,K] f32 (AIN=0) or bf16 (AIN=1) row-major. Wt: [M,K] bf16 row-major.
// BM=32*WM (WM=4 ->128, WM=2 ->64), BN=128, BK=64. 256 thr = 4 waves (2x2).
// PRE: 0=none 1=silu   EPI: 0=none 1=gelu 2=res+val 3=res+gate*val (gate bf16)
// OUTBF: 0=f32 out, 1=bf16 out
// ---------------------------------------------------------------------------
template<int WM, int AIN, int PRE, int EPI, int OUTBF>
__global__ __launch_bounds__(256) void gemm_mfma(
    const void* __restrict__ Ain, const unsigned short* __restrict__ Wt,
    const float* __restrict__ bias, void* __restrict__ Cout,
    const float* __restrict__ res, const void* __restrict__ gatep,
    int Nrows, int K, int M)
{
    constexpr int BM = 32 * WM;
    __shared__ unsigned short As[BM][64];
    __shared__ unsigned short Bs[128][64];
    const int tid = threadIdx.x;
    const int row0 = blockIdx.x * BM;
    const int col0 = blockIdx.y * 128;
    const int lane = tid & 63;
    const int wid  = tid >> 6;
    const int wr = (wid >> 1) * (16 * WM / 2) * 2;   // (wid>>1)*16*WM
    const int wc = (wid & 1) * 64;
    const int lr = lane & 15;
    const int lk = lane >> 4;

    f32x4 acc[WM][4];
#pragma unroll
    for (int i = 0; i < WM; i++)
#pragma unroll
        for (int j = 0; j < 4; j++) acc[i][j] = (f32x4)0.f;

    for (int k0 = 0; k0 < K; k0 += 64) {
        // stage A
#pragma unroll
        for (int i = 0; i < BM * 8 / 256; i++) {
            int f = tid + i * 256;
            int m = f >> 3, b = f & 7;
            int r = row0 + m;
            ushort8 h;
            if (r < Nrows) {
                if (AIN == 1) {
                    h = *(const ushort8*)((const unsigned short*)Ain + (size_t)r * K + k0 + b * 8);
                } else {
                    const float* ap = (const float*)Ain + (size_t)r * K + k0 + b * 8;
                    float4 p0 = *(const float4*)ap;
                    float4 p1 = *(const float4*)(ap + 4);
                    float v[8] = {p0.x, p0.y, p0.z, p0.w, p1.x, p1.y, p1.z, p1.w};
                    if (PRE == 1) {
#pragma unroll
                        for (int j = 0; j < 8; j++) v[j] = silu_f(v[j]);
                    }
#pragma unroll
                    for (int j = 0; j < 8; j++) h[j] = f2bf(v[j]);
                }
            } else {
#pragma unroll
                for (int j = 0; j < 8; j++) h[j] = 0;
            }
            *(ushort8*)&As[m][((b ^ (m & 7))) * 8] = h;
        }
        // stage B
#pragma unroll
        for (int i = 0; i < 4; i++) {
            int f = tid + i * 256;
            int n = f >> 3, b = f & 7;
            ushort8 w = *(const ushort8*)(Wt + (size_t)(col0 + n) * K + k0 + b * 8);
            *(ushort8*)&Bs[n][((b ^ (n & 7))) * 8] = w;
        }
        __syncthreads();

        short8 afr[WM][2], bfr[4][2];
#pragma unroll
        for (int fr = 0; fr < WM; fr++)
#pragma unroll
            for (int s = 0; s < 2; s++) {
                int m = wr + fr * 16 + lr;
                int blk = (s * 4 + lk) ^ (m & 7);
                afr[fr][s] = *(const short8*)&As[m][blk * 8];
            }
#pragma unroll
        for (int fc = 0; fc < 4; fc++)
#pragma unroll
            for (int s = 0; s < 2; s++) {
                int n = wc + fc * 16 + lr;
                int blk = (s * 4 + lk) ^ (n & 7);
                bfr[fc][s] = *(const short8*)&Bs[n][blk * 8];
            }
#pragma unroll
        for (int fr = 0; fr < WM; fr++)
#pragma unroll
            for (int fc = 0; fc < 4; fc++)
#pragma unroll
                for (int s = 0; s < 2; s++)
                    acc[fr][fc] = __builtin_amdgcn_mfma_f32_16x16x32_bf16(
                        afr[fr][s], bfr[fc][s], acc[fr][fc], 0, 0, 0);
        __syncthreads();
    }

#pragma unroll
    for (int fr = 0; fr < WM; fr++) {
#pragma unroll
        for (int fc = 0; fc < 4; fc++) {
#pragma unroll
            for (int r = 0; r < 4; r++) {
                int row = row0 + wr + fr * 16 + (lane >> 4) * 4 + r;
                if (row >= Nrows) continue;
                int col = col0 + wc + fc * 16 + (lane & 15);
                float val = acc[fr][fc][r] + bias[col];
                size_t idx = (size_t)row * M + col;
                if (EPI == 1) val = gelu_f(val);
                else if (EPI == 2) val = res[idx] + val;
                else if (EPI == 3) val = res[idx] +
                    bf2f(((const unsigned short*)gatep)[(size_t)row * 768 + col]) * val;
                if (OUTBF) ((unsigned short*)Cout)[idx] = f2bf(val);
                else       ((float*)Cout)[idx] = val;
            }
        }
    }
}

// ---------------------------------------------------------------------------
// All weight transposes/conversions in one kernel. Layout targets [M][K] bf16.
// k/v outputs of the SA projection are PERMUTED so that QKV columns interleave
// k and v 4-wide: col(k dim d) = 512 + (d>>2)*8 + (d&3); v: +4.
// ---------------------------------------------------------------------------
__global__ __launch_bounds__(256) void conv_all(
    const float* __restrict__ qW, const float* __restrict__ qB,
    const float* __restrict__ kW, const float* __restrict__ kB,
    const float* __restrict__ vW, const float* __restrict__ vB,
    const float* __restrict__ sW, const float* __restrict__ sB,
    const float* __restrict__ f1W, const float* __restrict__ f2W,
    const float* __restrict__ adW,
    unsigned short* __restrict__ Wsa_t, float* __restrict__ bsa,
    unsigned short* __restrict__ fc1_t, unsigned short* __restrict__ fc2_t,
    unsigned short* __restrict__ ada_t)
{
    int g = blockIdx.x * 256 + threadIdx.x;
    if (g < 65536) {                       // sa_q
        int m = g >> 7, kk = g & 127;
        Wsa_t[m * 128 + kk] = f2bf(qW[(size_t)kk * 512 + m]);
        if (kk == 0) bsa[m] = qB[m];
    } else if (g < 131072) {               // sa_k (interleaved)
        int l = g - 65536; int m = l >> 7, kk = l & 127;
        int p = 512 + ((m >> 2) << 3) + (m & 3);
        Wsa_t[p * 128 + kk] = f2bf(kW[(size_t)kk * 512 + m]);
        if (kk == 0) bsa[p] = kB[m];
    } else if (g < 196608) {               // sa_v (interleaved)
        int l = g - 131072; int m = l >> 7, kk = l & 127;
        int p = 516 + ((m >> 2) << 3) + (m & 3);
        Wsa_t[p * 128 + kk] = f2bf(vW[(size_t)kk * 512 + m]);
        if (kk == 0) bsa[p] = vB[m];
    } else if (g < 212992) {               // sa_skip
        int l = g - 196608; int m = l >> 7, kk = l & 127;
        Wsa_t[(1536 + m) * 128 + kk] = f2bf(sW[(size_t)kk * 128 + m]);
        if (kk == 0) bsa[1536 + m] = sB[m];
    } else if (g < 278528) {               // fc1
        int l = g - 212992; int m = l >> 7, kk = l & 127;
        fc1_t[m * 128 + kk] = f2bf(f1W[(size_t)kk * 512 + m]);
    } else if (g < 344064) {               // fc2
        int l = g - 278528; int m = l >> 9, kk = l & 511;
        fc2_t[m * 512 + kk] = f2bf(f2W[(size_t)kk * 128 + m]);
    } else if (g < 442368) {               // ada
        int l = g - 344064; int m = l >> 7, kk = l & 127;
        ada_t[m * 128 + kk] = f2bf(adW[(size_t)kk * 768 + m]);
    }
}

// ---------------------------------------------------------------------------
// Folded cross-attention weights (bf16, pre-transposed [M,K])
// ---------------------------------------------------------------------------
__global__ __launch_bounds__(256) void prep_weights(
    const float* __restrict__ Wq, const float* __restrict__ bq,
    const float* __restrict__ Wk, const float* __restrict__ Wv,
    const float* __restrict__ bv, const float* __restrict__ Wo,
    const float* __restrict__ bo,
    unsigned short* __restrict__ Mcat_t, float* __restrict__ biasM,
    unsigned short* __restrict__ Pcat_t, float* __restrict__ co)
{
    int g = blockIdx.x * 256 + threadIdx.x;   // 0..65535
    {
        int i0 = g >> 9, col = g & 511, h = col >> 7, i = col & 127;
        float s = 0.f;
#pragma unroll 8
        for (int j = 0; j < 32; j++)
            s += Wq[i0 * 128 + h * 32 + j] * Wk[i * 128 + h * 32 + j];
        Mcat_t[col * 128 + i0] = f2bf(s);
    }
    {
        int rowp = g >> 7, j = g & 127, h = rowp >> 7, i = rowp & 127;
        float s = 0.f;
#pragma unroll 8
        for (int d = 0; d < 32; d++)
            s += Wv[i * 128 + h * 32 + d] * Wo[(h * 32 + d) * 128 + j];
        Pcat_t[j * 512 + rowp] = f2bf(s);
    }
    if (g < 512) {
        int h = g >> 7, i = g & 127;
        float s = 0.f;
        for (int j = 0; j < 32; j++)
            s += bq[h * 32 + j] * Wk[i * 128 + h * 32 + j];
        biasM[g] = s;
    }
    if (g < 128) {
        float s = bo[g];
        for (int m = 0; m < 128; m++) s += bv[m] * Wo[m * 128 + g];
        co[g] = s;
    }
}

// ---------------------------------------------------------------------------
__device__ __forceinline__ void ln_stats(float v, int t, float& mu, float& rs) {
    float s = v, ss = v * v;
#pragma unroll
    for (int m = 1; m < 64; m <<= 1) { s += __shfl_xor(s, m); ss += __shfl_xor(ss, m); }
    __shared__ float l_s[2], l_ss[2];
    int w = t >> 6;
    if ((t & 63) == 0) { l_s[w] = s; l_ss[w] = ss; }
    __syncthreads();
    float S = l_s[0] + l_s[1], SS = l_ss[0] + l_ss[1];
    mu = S * (1.f / 128.f);
    float var = SS * (1.f / 128.f) - mu * mu;
    rs = rsqrtf(var + 1e-6f);
}

// LN + modulate; mod is bf16; output bf16
__global__ __launch_bounds__(128) void ln_mod_kernel(
    const float* __restrict__ x, const unsigned short* __restrict__ mod,
    int shift_off, int scale_off, unsigned short* __restrict__ outb)
{
    int node = blockIdx.x, t = threadIdx.x;
    float v = x[(size_t)node * 128 + t];
    float mu, rs;
    ln_stats(v, t, mu, rs);
    float xn = (v - mu) * rs;
    float shift = bf2f(mod[(size_t)node * 768 + shift_off + t]);
    float scale = bf2f(mod[(size_t)node * 768 + scale_off + t]);
    outb[(size_t)node * 128 + t] = f2bf(xn * (1.f + scale) + shift);
}

// ---------------------------------------------------------------------------
// CSR build
// ---------------------------------------------------------------------------
__global__ void count_edges(const int* __restrict__ dst, int* __restrict__ count, int E) {
    int e = blockIdx.x * blockDim.x + threadIdx.x;
    if (e < E) atomicAdd(&count[dst[e]], 1);
}

__global__ __launch_bounds__(1024) void scan_kernel(
    const int* __restrict__ count, int* __restrict__ base,
    int* __restrict__ cursor, int n)
{
    __shared__ int tmp[1024];
    int tid = threadIdx.x;
    int carry = 0;
    if (tid == 0) base[0] = 0;
    for (int start = 0; start < n; start += 1024) {
        int idx = start + tid;
        int v = (idx < n) ? count[idx] : 0;
        tmp[tid] = v;
        __syncthreads();
        for (int off = 1; off < 1024; off <<= 1) {
            int add = (tid >= off) ? tmp[tid - off] : 0;
            __syncthreads();
            tmp[tid] += add;
            __syncthreads();
        }
        if (idx < n) {
            base[idx + 1] = carry + tmp[tid];
            cursor[idx] = carry + tmp[tid] - v;
        }
        carry += tmp[1023];
        __syncthreads();
    }
}

__global__ void scatter_edges(const int* __restrict__ src, const int* __restrict__ dst,
                              int* __restrict__ cursor, int* __restrict__ csr_src, int E) {
    int e = blockIdx.x * blockDim.x + threadIdx.x;
    if (e < E) {
        int pos = atomicAdd(&cursor[dst[e]], 1);
        csr_src[pos] = src[e];
    }
}

// ---------------------------------------------------------------------------
// Graph self-attention + residual + fused norm3 LN.
// QKV layout per node (1664 bf16): q[0..511], kv interleaved [512..1535]
// (lane t: k at 512+t*8+0..3, v at +4..7), skip [1536..1663].
// Softmax without max-subtraction (logits are O(1); clamped at 80).
// Outputs: x1 (f32, residual stream), qn = LN(x1)*g+b (bf16).
// ---------------------------------------------------------------------------
__global__ __launch_bounds__(128) void sa_node_kernel(
    const unsigned short* __restrict__ qkv,
    const int* __restrict__ base, const int* __restrict__ csr_src,
    const float* __restrict__ x, const unsigned short* __restrict__ mod,
    const float* __restrict__ n3g, const float* __restrict__ n3b,
    float* __restrict__ x1, unsigned short* __restrict__ qn)
{
    int node = blockIdx.x, t = threadIdx.x;
    const size_t nb = (size_t)node * 1664;
    ushort4 qu = *(const ushort4*)(qkv + nb + t * 4);
    const float sc = 0.08838834764831845f;   // 1/sqrt(128)
    float q0 = bf2f(qu.x) * sc, q1 = bf2f(qu.y) * sc;
    float q2 = bf2f(qu.z) * sc, q3 = bf2f(qu.w) * sc;
    int beg = base[node], end = base[node + 1];
    float den = 0.f, a0 = 0.f, a1 = 0.f, a2 = 0.f, a3 = 0.f;
    ushort8 kva = (ushort8)0, kvb = (ushort8)0;
    if (beg < end)
        kva = *(const ushort8*)(qkv + (size_t)csr_src[beg] * 1664 + 512 + t * 8);
    if (beg + 1 < end)
        kvb = *(const ushort8*)(qkv + (size_t)csr_src[beg + 1] * 1664 + 512 + t * 8);
    for (int e = beg; e < end; e++) {
        ushort8 cur = kva;
        kva = kvb;
        if (e + 2 < end)
            kvb = *(const ushort8*)(qkv + (size_t)csr_src[e + 2] * 1664 + 512 + t * 8);
        float p = q0 * bf2f(cur[0]) + q1 * bf2f(cur[1])
                + q2 * bf2f(cur[2]) + q3 * bf2f(cur[3]);
#pragma unroll
        for (int mm = 1; mm < 32; mm <<= 1) p += __shfl_xor(p, mm);
        float pe = __expf(fminf(p, 80.f));
        den += pe;
        a0 += pe * bf2f(cur[4]);
        a1 += pe * bf2f(cur[5]);
        a2 += pe * bf2f(cur[6]);
        a3 += pe * bf2f(cur[7]);
    }
    float inv = (den > 0.f) ? 0.25f / den : 0.f;   // mean over 4 heads folded in
    __shared__ float red[512];
    *(float4*)&red[t * 4] = make_float4(a0 * inv, a1 * inv, a2 * inv, a3 * inv);
    __syncthreads();
    float sa = red[t] + red[128 + t] + red[256 + t] + red[384 + t];
    float sab = bf2f(qkv[nb + 1536 + t]);
    float g = bf2f(mod[(size_t)node * 768 + 256 + t]);
    size_t idx = (size_t)node * 128 + t;
    float xv = x[idx] + g * (sa + sab);
    x1[idx] = xv;
    // fused norm3
    float mu, rs;
    ln_stats(xv, t, mu, rs);
    qn[idx] = f2bf((xv - mu) * rs * n3g[t] + n3b[t]);
}

// ---------------------------------------------------------------------------
// Cross-attention middle: scores = (te @ qw^T)/sqrt(32), softmax over L=32,
// u[h,:] = attn[h,:] @ te.  qw bf16 in, u bf16 out. te f32 staged in LDS.
// ---------------------------------------------------------------------------
__global__ __launch_bounds__(128) void cross_mid_kernel(
    const float* __restrict__ te, const unsigned short* __restrict__ qw,
    unsigned short* __restrict__ u)
{
    int node = blockIdx.x, t = threadIdx.x;
    __shared__ float tes[32 * 132];
    __shared__ float qws[512];
    __shared__ float attnL[128];
#pragma unroll
    for (int i = 0; i < 8; i++) {
        int f = t + i * 128;
        int l = f >> 5, ii = (f & 31) * 4;
        float4 val = *(const float4*)(te + (size_t)node * 4096 + l * 128 + ii);
        *(float4*)&tes[l * 132 + ii] = val;
    }
    {
        ushort4 qv = *(const ushort4*)(qw + (size_t)node * 512 + t * 4);
        qws[t * 4 + 0] = bf2f(qv.x);
        qws[t * 4 + 1] = bf2f(qv.y);
        qws[t * 4 + 2] = bf2f(qv.z);
        qws[t * 4 + 3] = bf2f(qv.w);
    }
    __syncthreads();

    int h = t >> 5, l = t & 31;
    float sc = 0.f;
#pragma unroll 8
    for (int i = 0; i < 128; i++) sc += tes[l * 132 + i] * qws[h * 128 + i];
    sc *= 0.17677669529663687f;  // 1/sqrt(32)
    float mx = sc;
#pragma unroll
    for (int mm = 1; mm < 32; mm <<= 1) mx = fmaxf(mx, __shfl_xor(mx, mm));
    float e = __expf(sc - mx);
    float ssum = e;
#pragma unroll
    for (int mm = 1; mm < 32; mm <<= 1) ssum += __shfl_xor(ssum, mm);
    attnL[t] = e / ssum;
    __syncthreads();

    int i0 = t & 31;
    float u0 = 0, u1 = 0, u2 = 0, u3 = 0;
#pragma unroll 4
    for (int ll = 0; ll < 32; ll++) {
        float a = attnL[h * 32 + ll];
        u0 += a * tes[ll * 132 + i0];
        u1 += a * tes[ll * 132 + i0 + 32];
        u2 += a * tes[ll * 132 + i0 + 64];
        u3 += a * tes[ll * 132 + i0 + 96];
    }
    size_t ub = (size_t)node * 512 + h * 128;
    u[ub + i0] = f2bf(u0);
    u[ub + i0 + 32] = f2bf(u1);
    u[ub + i0 + 64] = f2bf(u2);
    u[ub + i0 + 96] = f2bf(u3);
}

// ---------------------------------------------------------------------------
extern "C" void kernel_launch(void* const* d_in, const int* in_sizes, int n_in,
                              void* d_out, int out_size, void* d_ws, size_t ws_size,
                              hipStream_t stream)
{
    const int N = in_sizes[0] / 128;        // 20000
    const int E = in_sizes[1] / 2;          // 320000

    const float* x      = (const float*)d_in[0];
    const int*   ei     = (const int*)d_in[1];
    const float* t_in   = (const float*)d_in[2];
    const float* te     = (const float*)d_in[3];
    const float* sa_q_w = (const float*)d_in[4];
    const float* sa_q_b = (const float*)d_in[5];
    const float* sa_k_w = (const float*)d_in[6];
    const float* sa_k_b = (const float*)d_in[7];
    const float* sa_v_w = (const float*)d_in[8];
    const float* sa_v_b = (const float*)d_in[9];
    const float* sa_skip_w = (const float*)d_in[10];
    const float* sa_skip_b = (const float*)d_in[11];
    const float* n3_g   = (const float*)d_in[12];
    const float* n3_b   = (const float*)d_in[13];
    const float* mha_q_w = (const float*)d_in[14];
    const float* mha_q_b = (const float*)d_in[15];
    const float* mha_k_w = (const float*)d_in[16];
    const float* mha_v_w = (const float*)d_in[18];
    const float* mha_v_b = (const float*)d_in[19];
    const float* mha_o_w = (const float*)d_in[20];
    const float* mha_o_b = (const float*)d_in[21];
    const float* fc1_w  = (const float*)d_in[22];
    const float* fc1_b  = (const float*)d_in[23];
    const float* fc2_w  = (const float*)d_in[24];
    const float* fc2_b  = (const float*)d_in[25];
    const float* ada_w  = (const float*)d_in[26];
    const float* ada_b  = (const float*)d_in[27];
    float* out = (float*)d_out;

    // workspace layout (float units, 16B-aligned throughout)
    float* ws = (float*)d_ws;
    size_t o = 0;
    unsigned short* modb = (unsigned short*)(ws + o); o += (size_t)N * 384; // [N,768] bf16
    unsigned short* Bbuf = (unsigned short*)(ws + o); o += (size_t)N * 64;  // xm/xm2 bf16
    unsigned short* Qn   = (unsigned short*)(ws + o); o += (size_t)N * 64;  // qn bf16
    unsigned short* Cbuf = (unsigned short*)(ws + o); o += (size_t)N * 256; // qw bf16
    unsigned short* Dbuf = (unsigned short*)(ws + o); o += (size_t)N * 256; // u bf16
    unsigned short* Ebuf = (unsigned short*)(ws + o); o += (size_t)N * 256; // h bf16
    float* Gbuf = ws + o; o += (size_t)N * 128;                             // x1 -> x2 f32
    unsigned short* QKV = (unsigned short*)(ws + o); o += (size_t)N * 832;  // [N,1664] bf16
    unsigned short* Wsa_t  = (unsigned short*)(ws + o); o += 1664 * 128 / 2;
    unsigned short* Mcat_t = (unsigned short*)(ws + o); o += 512 * 128 / 2;
    unsigned short* Pcat_t = (unsigned short*)(ws + o); o += 128 * 512 / 2;
    unsigned short* fc1_t  = (unsigned short*)(ws + o); o += 512 * 128 / 2;
    unsigned short* fc2_t  = (unsigned short*)(ws + o); o += 128 * 512 / 2;
    unsigned short* ada_t  = (unsigned short*)(ws + o); o += 768 * 128 / 2;
    float* bsa   = ws + o; o += 1664;
    float* biasM = ws + o; o += 512;
    float* co    = ws + o; o += 128;
    int* count   = (int*)(ws + o); o += N;
    int* base    = (int*)(ws + o); o += N + 4;
    int* cursor  = (int*)(ws + o); o += N;
    int* csr_src = (int*)(ws + o); o += E;

    const int* src = ei;
    const int* dst = ei + E;
    const int rb128 = (N + 127) / 128;   // 157
    const int rb64  = (N + 63) / 64;     // 313

    // ---- weight prep ----
    conv_all<<<1728, 256, 0, stream>>>(sa_q_w, sa_q_b, sa_k_w, sa_k_b,
                                       sa_v_w, sa_v_b, sa_skip_w, sa_skip_b,
                                       fc1_w, fc2_w, ada_w,
                                       Wsa_t, bsa, fc1_t, fc2_t, ada_t);
    prep_weights<<<256, 256, 0, stream>>>(mha_q_w, mha_q_b, mha_k_w, mha_v_w,
                                          mha_v_b, mha_o_w, mha_o_b,
                                          Mcat_t, biasM, Pcat_t, co);

    // ---- CSR build ----
    hipMemsetAsync(count, 0, (size_t)N * sizeof(int), stream);
    count_edges<<<(E + 255) / 256, 256, 0, stream>>>(dst, count, E);
    scan_kernel<<<1, 1024, 0, stream>>>(count, base, cursor, N);
    scatter_edges<<<(E + 255) / 256, 256, 0, stream>>>(src, dst, cursor, csr_src, E);

    // ---- adaLN: mod = silu(t) @ ada_w + ada_b  (bf16 out) ----
    gemm_mfma<4, 0, 1, 0, 1><<<dim3(rb128, 6), 256, 0, stream>>>(
        t_in, ada_t, ada_b, modb, nullptr, nullptr, N, 128, 768);

    // ---- xm = modulate(ln(x), shift_msa, scale_msa) ----
    ln_mod_kernel<<<N, 128, 0, stream>>>(x, modb, 0, 128, Bbuf);

    // ---- fused q|kv|skip GEMM -> bf16 [N,1664] ----
    gemm_mfma<4, 1, 0, 0, 1><<<dim3(rb128, 13), 256, 0, stream>>>(
        Bbuf, Wsa_t, bsa, QKV, nullptr, nullptr, N, 128, 1664);

    // ---- graph attention + residual + fused norm3 -> x1 (f32), qn (bf16) ----
    sa_node_kernel<<<N, 128, 0, stream>>>(QKV, base, csr_src, x, modb,
                                          n3_g, n3_b, Gbuf, Qn);

    // ---- cross attention (folded) ----
    gemm_mfma<4, 1, 0, 0, 1><<<dim3(rb128, 4), 256, 0, stream>>>(
        Qn, Mcat_t, biasM, Cbuf, nullptr, nullptr, N, 128, 512);
    cross_mid_kernel<<<N, 128, 0, stream>>>(te, Cbuf, Dbuf);
    gemm_mfma<2, 1, 0, 2, 0><<<dim3(rb64, 1), 256, 0, stream>>>(
        Dbuf, Pcat_t, co, Gbuf, Gbuf, nullptr, N, 512, 128);   // x2 = x1 + u@Pcat + co

    // ---- MLP ----
    ln_mod_kernel<<<N, 128, 0, stream>>>(Gbuf, modb, 384, 512, Bbuf);
    gemm_mfma<4, 1, 0, 1, 1><<<dim3(rb128, 4), 256, 0, stream>>>(
        Bbuf, fc1_t, fc1_b, Ebuf, nullptr, nullptr, N, 128, 512);
    gemm_mfma<2, 1, 0, 3, 0><<<dim3(rb64, 1), 256, 0, stream>>>(
        Ebuf, fc2_t, fc2_b, out, Gbuf, modb + 640, N, 512, 128);
}

// Round 4
// 382.599 us; speedup vs baseline: 2.8211x; 1.1757x over previous
//
#include <hip/hip_runtime.h>
#include <hip/hip_bf16.h>
#include <math.h>

using ushort8 = __attribute__((ext_vector_type(8))) unsigned short;
using short8  = __attribute__((ext_vector_type(8))) short;
using f32x4   = __attribute__((ext_vector_type(4))) float;
using f32x2   = __attribute__((ext_vector_type(2))) float;

__device__ __forceinline__ float bf2f(unsigned short u) {
    union { unsigned int i; float f; } c; c.i = ((unsigned int)u) << 16; return c.f;
}
__device__ __forceinline__ unsigned short f2bf(float f) {
    __hip_bfloat16 h = __float2bfloat16(f);
    return *reinterpret_cast<unsigned short*>(&h);
}
__device__ __forceinline__ float silu_f(float x) { return x / (1.f + __expf(-x)); }
__device__ __forceinline__ float gelu_f(float x) {
    float x3 = x * x * x;
    return 0.5f * x * (1.f + tanhf(0.7978845608028654f * (x + 0.044715f * x3)));
}

// QKV packed row: 2304 bytes = q[512] bf16 | kv[1024] fp8 (k4|v4 per lane) | skip[128] bf16
constexpr int QKV_STRIDE_B = 2304;

// ---------------------------------------------------------------------------
// bf16 MFMA GEMM: C = epi(pre(A) @ Wt^T + bias)
// A: [N,K] f32 (AIN=0) or bf16 (AIN=1). Wt: [M,K] bf16 row-major.
// BM=32*WM, BN=128, BK=64. 256 thr = 4 waves (2x2).
// PRE: 0=none 1=silu
// EPI: 0=none 1=gelu 2=res+val 3=res+gate*val (gate bf16) 4=qkv packed store
// OUTBF: 0=f32 out, 1=bf16 out (ignored for EPI=4)
// ---------------------------------------------------------------------------
template<int WM, int AIN, int PRE, int EPI, int OUTBF>
__global__ __launch_bounds__(256) void gemm_mfma(
    const void* __restrict__ Ain, const unsigned short* __restrict__ Wt,
    const float* __restrict__ bias, void* __restrict__ Cout,
    const float* __restrict__ res, const void* __restrict__ gatep,
    int Nrows, int K, int M)
{
    constexpr int BM = 32 * WM;
    __shared__ unsigned short As[BM][64];
    __shared__ unsigned short Bs[128][64];
    const int tid = threadIdx.x;
    const int row0 = blockIdx.x * BM;
    const int col0 = blockIdx.y * 128;
    const int lane = tid & 63;
    const int wid  = tid >> 6;
    const int wr = (wid >> 1) * 16 * WM;
    const int wc = (wid & 1) * 64;
    const int lr = lane & 15;
    const int lk = lane >> 4;

    f32x4 acc[WM][4];
#pragma unroll
    for (int i = 0; i < WM; i++)
#pragma unroll
        for (int j = 0; j < 4; j++) acc[i][j] = (f32x4)0.f;

    for (int k0 = 0; k0 < K; k0 += 64) {
#pragma unroll
        for (int i = 0; i < BM * 8 / 256; i++) {
            int f = tid + i * 256;
            int m = f >> 3, b = f & 7;
            int r = row0 + m;
            ushort8 h;
            if (r < Nrows) {
                if (AIN == 1) {
                    h = *(const ushort8*)((const unsigned short*)Ain + (size_t)r * K + k0 + b * 8);
                } else {
                    const float* ap = (const float*)Ain + (size_t)r * K + k0 + b * 8;
                    float4 p0 = *(const float4*)ap;
                    float4 p1 = *(const float4*)(ap + 4);
                    float v[8] = {p0.x, p0.y, p0.z, p0.w, p1.x, p1.y, p1.z, p1.w};
                    if (PRE == 1) {
#pragma unroll
                        for (int j = 0; j < 8; j++) v[j] = silu_f(v[j]);
                    }
#pragma unroll
                    for (int j = 0; j < 8; j++) h[j] = f2bf(v[j]);
                }
            } else {
#pragma unroll
                for (int j = 0; j < 8; j++) h[j] = 0;
            }
            *(ushort8*)&As[m][((b ^ (m & 7))) * 8] = h;
        }
#pragma unroll
        for (int i = 0; i < 4; i++) {
            int f = tid + i * 256;
            int n = f >> 3, b = f & 7;
            ushort8 w = *(const ushort8*)(Wt + (size_t)(col0 + n) * K + k0 + b * 8);
            *(ushort8*)&Bs[n][((b ^ (n & 7))) * 8] = w;
        }
        __syncthreads();

        short8 afr[WM][2], bfr[4][2];
#pragma unroll
        for (int fr = 0; fr < WM; fr++)
#pragma unroll
            for (int s = 0; s < 2; s++) {
                int m = wr + fr * 16 + lr;
                int blk = (s * 4 + lk) ^ (m & 7);
                afr[fr][s] = *(const short8*)&As[m][blk * 8];
            }
#pragma unroll
        for (int fc = 0; fc < 4; fc++)
#pragma unroll
            for (int s = 0; s < 2; s++) {
                int n = wc + fc * 16 + lr;
                int blk = (s * 4 + lk) ^ (n & 7);
                bfr[fc][s] = *(const short8*)&Bs[n][blk * 8];
            }
#pragma unroll
        for (int fr = 0; fr < WM; fr++)
#pragma unroll
            for (int fc = 0; fc < 4; fc++)
#pragma unroll
                for (int s = 0; s < 2; s++)
                    acc[fr][fc] = __builtin_amdgcn_mfma_f32_16x16x32_bf16(
                        afr[fr][s], bfr[fc][s], acc[fr][fc], 0, 0, 0);
        __syncthreads();
    }

#pragma unroll
    for (int fr = 0; fr < WM; fr++) {
#pragma unroll
        for (int fc = 0; fc < 4; fc++) {
#pragma unroll
            for (int r = 0; r < 4; r++) {
                int row = row0 + wr + fr * 16 + (lane >> 4) * 4 + r;
                if (row >= Nrows) continue;
                int col = col0 + wc + fc * 16 + (lane & 15);
                float val = acc[fr][fc][r] + bias[col];
                if (EPI == 4) {
                    unsigned char* rowp = (unsigned char*)Cout + (size_t)row * QKV_STRIDE_B;
                    if (col < 512) {
                        *(unsigned short*)(rowp + 2 * col) = f2bf(val);
                    } else if (col < 1536) {
                        int p = __builtin_amdgcn_cvt_pk_fp8_f32(val, 0.f, 0, false);
                        rowp[1024 + (col - 512)] = (unsigned char)(p & 0xff);
                    } else {
                        *(unsigned short*)(rowp + 2048 + 2 * (col - 1536)) = f2bf(val);
                    }
                } else {
                    size_t idx = (size_t)row * M + col;
                    if (EPI == 1) val = gelu_f(val);
                    else if (EPI == 2) val = res[idx] + val;
                    else if (EPI == 3) val = res[idx] +
                        bf2f(((const unsigned short*)gatep)[(size_t)row * 768 + col]) * val;
                    if (OUTBF) ((unsigned short*)Cout)[idx] = f2bf(val);
                    else       ((float*)Cout)[idx] = val;
                }
            }
        }
    }
}

// ---------------------------------------------------------------------------
// All weight transposes/conversions. Targets [M][K] bf16. k/v cols interleaved
// 4-wide: k dim d -> col 512+(d>>2)*8+(d&3); v dim d -> +4.
// ---------------------------------------------------------------------------
__global__ __launch_bounds__(256) void conv_all(
    const float* __restrict__ qW, const float* __restrict__ qB,
    const float* __restrict__ kW, const float* __restrict__ kB,
    const float* __restrict__ vW, const float* __restrict__ vB,
    const float* __restrict__ sW, const float* __restrict__ sB,
    const float* __restrict__ f1W, const float* __restrict__ f2W,
    const float* __restrict__ adW,
    unsigned short* __restrict__ Wsa_t, float* __restrict__ bsa,
    unsigned short* __restrict__ fc1_t, unsigned short* __restrict__ fc2_t,
    unsigned short* __restrict__ ada_t)
{
    int g = blockIdx.x * 256 + threadIdx.x;
    if (g < 65536) {                       // sa_q
        int m = g >> 7, kk = g & 127;
        Wsa_t[m * 128 + kk] = f2bf(qW[(size_t)kk * 512 + m]);
        if (kk == 0) bsa[m] = qB[m];
    } else if (g < 131072) {               // sa_k (interleaved)
        int l = g - 65536; int m = l >> 7, kk = l & 127;
        int p = 512 + ((m >> 2) << 3) + (m & 3);
        Wsa_t[p * 128 + kk] = f2bf(kW[(size_t)kk * 512 + m]);
        if (kk == 0) bsa[p] = kB[m];
    } else if (g < 196608) {               // sa_v (interleaved)
        int l = g - 131072; int m = l >> 7, kk = l & 127;
        int p = 516 + ((m >> 2) << 3) + (m & 3);
        Wsa_t[p * 128 + kk] = f2bf(vW[(size_t)kk * 512 + m]);
        if (kk == 0) bsa[p] = vB[m];
    } else if (g < 212992) {               // sa_skip
        int l = g - 196608; int m = l >> 7, kk = l & 127;
        Wsa_t[(1536 + m) * 128 + kk] = f2bf(sW[(size_t)kk * 128 + m]);
        if (kk == 0) bsa[1536 + m] = sB[m];
    } else if (g < 278528) {               // fc1
        int l = g - 212992; int m = l >> 7, kk = l & 127;
        fc1_t[m * 128 + kk] = f2bf(f1W[(size_t)kk * 512 + m]);
    } else if (g < 344064) {               // fc2
        int l = g - 278528; int m = l >> 9, kk = l & 511;
        fc2_t[m * 512 + kk] = f2bf(f2W[(size_t)kk * 128 + m]);
    } else if (g < 442368) {               // ada
        int l = g - 344064; int m = l >> 7, kk = l & 127;
        ada_t[m * 128 + kk] = f2bf(adW[(size_t)kk * 768 + m]);
    }
}

// ---------------------------------------------------------------------------
// Folded cross-attention weights (bf16, pre-transposed [M,K])
// ---------------------------------------------------------------------------
__global__ __launch_bounds__(256) void prep_weights(
    const float* __restrict__ Wq, const float* __restrict__ bq,
    const float* __restrict__ Wk, const float* __restrict__ Wv,
    const float* __restrict__ bv, const float* __restrict__ Wo,
    const float* __restrict__ bo,
    unsigned short* __restrict__ Mcat_t, float* __restrict__ biasM,
    unsigned short* __restrict__ Pcat_t, float* __restrict__ co)
{
    int g = blockIdx.x * 256 + threadIdx.x;   // 0..65535
    {
        int i0 = g >> 9, col = g & 511, h = col >> 7, i = col & 127;
        float s = 0.f;
#pragma unroll 8
        for (int j = 0; j < 32; j++)
            s += Wq[i0 * 128 + h * 32 + j] * Wk[i * 128 + h * 32 + j];
        Mcat_t[col * 128 + i0] = f2bf(s);
    }
    {
        int rowp = g >> 7, j = g & 127, h = rowp >> 7, i = rowp & 127;
        float s = 0.f;
#pragma unroll 8
        for (int d = 0; d < 32; d++)
            s += Wv[i * 128 + h * 32 + d] * Wo[(h * 32 + d) * 128 + j];
        Pcat_t[j * 512 + rowp] = f2bf(s);
    }
    if (g < 512) {
        int h = g >> 7, i = g & 127;
        float s = 0.f;
        for (int j = 0; j < 32; j++)
            s += bq[h * 32 + j] * Wk[i * 128 + h * 32 + j];
        biasM[g] = s;
    }
    if (g < 128) {
        float s = bo[g];
        for (int m = 0; m < 128; m++) s += bv[m] * Wo[m * 128 + g];
        co[g] = s;
    }
}

// ---------------------------------------------------------------------------
// LN + modulate, one WAVE per node (64 lanes x 2 elems), no LDS.
// ---------------------------------------------------------------------------
__global__ __launch_bounds__(256) void ln_mod_kernel(
    const float* __restrict__ x, const unsigned short* __restrict__ mod,
    int shift_off, int scale_off, unsigned short* __restrict__ outb, int N)
{
    int node = blockIdx.x * 4 + (threadIdx.x >> 6);
    if (node >= N) return;
    int lane = threadIdx.x & 63;
    f32x2 v = *(const f32x2*)(x + (size_t)node * 128 + lane * 2);
    float s = v[0] + v[1], ss = v[0] * v[0] + v[1] * v[1];
#pragma unroll
    for (int m = 1; m < 64; m <<= 1) { s += __shfl_xor(s, m); ss += __shfl_xor(ss, m); }
    float mu = s * (1.f / 128.f);
    float rs = rsqrtf(ss * (1.f / 128.f) - mu * mu + 1e-6f);
    const unsigned short* mp = mod + (size_t)node * 768;
    ushort2 sh = *(const ushort2*)(mp + shift_off + lane * 2);
    ushort2 sc = *(const ushort2*)(mp + scale_off + lane * 2);
    ushort2 o;
    o.x = f2bf((v[0] - mu) * rs * (1.f + bf2f(sc.x)) + bf2f(sh.x));
    o.y = f2bf((v[1] - mu) * rs * (1.f + bf2f(sc.y)) + bf2f(sh.y));
    *(ushort2*)(outb + (size_t)node * 128 + lane * 2) = o;
}

// ---------------------------------------------------------------------------
// CSR build: count -> parallel 3-phase scan -> scatter
// ---------------------------------------------------------------------------
__global__ void count_edges(const int* __restrict__ dst, int* __restrict__ count, int E) {
    int e = blockIdx.x * blockDim.x + threadIdx.x;
    if (e < E) atomicAdd(&count[dst[e]], 1);
}

__global__ __launch_bounds__(1024) void scan_block(const int* __restrict__ cnt,
                                                   int* __restrict__ pre,
                                                   int* __restrict__ bsum, int n)
{
    __shared__ int tmp[1024];
    int gid = blockIdx.x * 1024 + threadIdx.x;
    int v = (gid < n) ? cnt[gid] : 0;
    tmp[threadIdx.x] = v;
    __syncthreads();
    for (int off = 1; off < 1024; off <<= 1) {
        int add = (threadIdx.x >= off) ? tmp[threadIdx.x - off] : 0;
        __syncthreads();
        tmp[threadIdx.x] += add;
        __syncthreads();
    }
    if (gid < n) pre[gid] = tmp[threadIdx.x];
    if (threadIdx.x == 1023) bsum[blockIdx.x] = tmp[1023];
}

__global__ void scan_tops(int* __restrict__ bsum, int nb) {
    if (threadIdx.x == 0 && blockIdx.x == 0) {
        int c = 0;
        for (int i = 0; i < nb; i++) { int v = bsum[i]; bsum[i] = c; c += v; }
    }
}

__global__ void scan_fix(const int* __restrict__ pre, const int* __restrict__ bsum,
                         const int* __restrict__ cnt,
                         int* __restrict__ base, int* __restrict__ cursor, int n)
{
    int gid = blockIdx.x * 256 + threadIdx.x;
    if (gid < n) {
        int inc = pre[gid] + bsum[gid >> 10];
        base[gid + 1] = inc;
        cursor[gid] = inc - cnt[gid];
    }
    if (gid == 0) base[0] = 0;
}

__global__ void scatter_edges(const int* __restrict__ src, const int* __restrict__ dst,
                              int* __restrict__ cursor, int* __restrict__ csr_src, int E) {
    int e = blockIdx.x * blockDim.x + threadIdx.x;
    if (e < E) {
        int pos = atomicAdd(&cursor[dst[e]], 1);
        csr_src[pos] = src[e];
    }
}

// ---------------------------------------------------------------------------
// Graph self-attention + residual + fused norm3 LN.
// QKV packed row (2304B): q bf16 | kv fp8 interleaved | skip bf16.
// Lane t: k dims 4t..4t+3 at bytes 1024+8t..+3, v at +4..+7.
// ---------------------------------------------------------------------------
__global__ __launch_bounds__(128) void sa_node_kernel(
    const unsigned char* __restrict__ qkv,
    const int* __restrict__ base, const int* __restrict__ csr_src,
    const float* __restrict__ x, const unsigned short* __restrict__ mod,
    const float* __restrict__ n3g, const float* __restrict__ n3b,
    float* __restrict__ x1, unsigned short* __restrict__ qn)
{
    int node = blockIdx.x, t = threadIdx.x;
    const unsigned char* nrow = qkv + (size_t)node * QKV_STRIDE_B;
    ushort4 qu = *(const ushort4*)((const unsigned short*)nrow + t * 4);
    const float sc = 0.08838834764831845f;   // 1/sqrt(128)
    float q0 = bf2f(qu.x) * sc, q1 = bf2f(qu.y) * sc;
    float q2 = bf2f(qu.z) * sc, q3 = bf2f(qu.w) * sc;
    int beg = base[node], end = base[node + 1];
    float den = 0.f, a0 = 0.f, a1 = 0.f, a2 = 0.f, a3 = 0.f;
    uint2 kva = make_uint2(0, 0), kvb = make_uint2(0, 0);
    if (beg < end)
        kva = *(const uint2*)(qkv + (size_t)csr_src[beg] * QKV_STRIDE_B + 1024 + t * 8);
    if (beg + 1 < end)
        kvb = *(const uint2*)(qkv + (size_t)csr_src[beg + 1] * QKV_STRIDE_B + 1024 + t * 8);
    for (int e = beg; e < end; e++) {
        uint2 cur = kva;
        kva = kvb;
        if (e + 2 < end)
            kvb = *(const uint2*)(qkv + (size_t)csr_src[e + 2] * QKV_STRIDE_B + 1024 + t * 8);
        f32x2 k01 = __builtin_amdgcn_cvt_pk_f32_fp8(cur.x, false);
        f32x2 k23 = __builtin_amdgcn_cvt_pk_f32_fp8(cur.x, true);
        f32x2 v01 = __builtin_amdgcn_cvt_pk_f32_fp8(cur.y, false);
        f32x2 v23 = __builtin_amdgcn_cvt_pk_f32_fp8(cur.y, true);
        float p = q0 * k01[0] + q1 * k01[1] + q2 * k23[0] + q3 * k23[1];
#pragma unroll
        for (int mm = 1; mm < 32; mm <<= 1) p += __shfl_xor(p, mm);
        float pe = __expf(fminf(p, 80.f));
        den += pe;
        a0 += pe * v01[0];
        a1 += pe * v01[1];
        a2 += pe * v23[0];
        a3 += pe * v23[1];
    }
    float inv = (den > 0.f) ? 0.25f / den : 0.f;   // mean over 4 heads folded in
    __shared__ float red[512];
    *(float4*)&red[t * 4] = make_float4(a0 * inv, a1 * inv, a2 * inv, a3 * inv);
    __syncthreads();
    float sa = red[t] + red[128 + t] + red[256 + t] + red[384 + t];
    float sab = bf2f(*(const unsigned short*)(nrow + 2048 + 2 * t));
    float g = bf2f(mod[(size_t)node * 768 + 256 + t]);
    size_t idx = (size_t)node * 128 + t;
    float xv = x[idx] + g * (sa + sab);
    x1[idx] = xv;
    // fused norm3
    float s = xv, ssq = xv * xv;
#pragma unroll
    for (int m = 1; m < 64; m <<= 1) { s += __shfl_xor(s, m); ssq += __shfl_xor(ssq, m); }
    __shared__ float l_s[2], l_ss[2];
    int w = t >> 6;
    if ((t & 63) == 0) { l_s[w] = s; l_ss[w] = ssq; }
    __syncthreads();
    float S = l_s[0] + l_s[1], SS = l_ss[0] + l_ss[1];
    float mu = S * (1.f / 128.f);
    float rs = rsqrtf(SS * (1.f / 128.f) - mu * mu + 1e-6f);
    qn[idx] = f2bf((xv - mu) * rs * n3g[t] + n3b[t]);
}

// ---------------------------------------------------------------------------
// Cross-attention middle: scores = (te @ qw^T)/sqrt(32), softmax over L=32,
// u[h,:] = attn[h,:] @ te.  qw bf16 in, u bf16 out. te f32 staged in LDS.
// ---------------------------------------------------------------------------
__global__ __launch_bounds__(128) void cross_mid_kernel(
    const float* __restrict__ te, const unsigned short* __restrict__ qw,
    unsigned short* __restrict__ u)
{
    int node = blockIdx.x, t = threadIdx.x;
    __shared__ float tes[32 * 132];
    __shared__ float qws[512];
    __shared__ float attnL[128];
#pragma unroll
    for (int i = 0; i < 8; i++) {
        int f = t + i * 128;
        int l = f >> 5, ii = (f & 31) * 4;
        float4 val = *(const float4*)(te + (size_t)node * 4096 + l * 128 + ii);
        *(float4*)&tes[l * 132 + ii] = val;
    }
    {
        ushort4 qv = *(const ushort4*)(qw + (size_t)node * 512 + t * 4);
        qws[t * 4 + 0] = bf2f(qv.x);
        qws[t * 4 + 1] = bf2f(qv.y);
        qws[t * 4 + 2] = bf2f(qv.z);
        qws[t * 4 + 3] = bf2f(qv.w);
    }
    __syncthreads();

    int h = t >> 5, l = t & 31;
    float sc = 0.f;
#pragma unroll 8
    for (int i = 0; i < 128; i++) sc += tes[l * 132 + i] * qws[h * 128 + i];
    sc *= 0.17677669529663687f;  // 1/sqrt(32)
    float mx = sc;
#pragma unroll
    for (int mm = 1; mm < 32; mm <<= 1) mx = fmaxf(mx, __shfl_xor(mx, mm));
    float e = __expf(sc - mx);
    float ssum = e;
#pragma unroll
    for (int mm = 1; mm < 32; mm <<= 1) ssum += __shfl_xor(ssum, mm);
    attnL[t] = e / ssum;
    __syncthreads();

    int i0 = t & 31;
    float u0 = 0, u1 = 0, u2 = 0, u3 = 0;
#pragma unroll 4
    for (int ll = 0; ll < 32; ll++) {
        float a = attnL[h * 32 + ll];
        u0 += a * tes[ll * 132 + i0];
        u1 += a * tes[ll * 132 + i0 + 32];
        u2 += a * tes[ll * 132 + i0 + 64];
        u3 += a * tes[ll * 132 + i0 + 96];
    }
    size_t ub = (size_t)node * 512 + h * 128;
    u[ub + i0] = f2bf(u0);
    u[ub + i0 + 32] = f2bf(u1);
    u[ub + i0 + 64] = f2bf(u2);
    u[ub + i0 + 96] = f2bf(u3);
}

// ---------------------------------------------------------------------------
extern "C" void kernel_launch(void* const* d_in, const int* in_sizes, int n_in,
                              void* d_out, int out_size, void* d_ws, size_t ws_size,
                              hipStream_t stream)
{
    const int N = in_sizes[0] / 128;        // 20000
    const int E = in_sizes[1] / 2;          // 320000

    const float* x      = (const float*)d_in[0];
    const int*   ei     = (const int*)d_in[1];
    const float* t_in   = (const float*)d_in[2];
    const float* te     = (const float*)d_in[3];
    const float* sa_q_w = (const float*)d_in[4];
    const float* sa_q_b = (const float*)d_in[5];
    const float* sa_k_w = (const float*)d_in[6];
    const float* sa_k_b = (const float*)d_in[7];
    const float* sa_v_w = (const float*)d_in[8];
    const float* sa_v_b = (const float*)d_in[9];
    const float* sa_skip_w = (const float*)d_in[10];
    const float* sa_skip_b = (const float*)d_in[11];
    const float* n3_g   = (const float*)d_in[12];
    const float* n3_b   = (const float*)d_in[13];
    const float* mha_q_w = (const float*)d_in[14];
    const float* mha_q_b = (const float*)d_in[15];
    const float* mha_k_w = (const float*)d_in[16];
    const float* mha_v_w = (const float*)d_in[18];
    const float* mha_v_b = (const float*)d_in[19];
    const float* mha_o_w = (const float*)d_in[20];
    const float* mha_o_b = (const float*)d_in[21];
    const float* fc1_w  = (const float*)d_in[22];
    const float* fc1_b  = (const float*)d_in[23];
    const float* fc2_w  = (const float*)d_in[24];
    const float* fc2_b  = (const float*)d_in[25];
    const float* ada_w  = (const float*)d_in[26];
    const float* ada_b  = (const float*)d_in[27];
    float* out = (float*)d_out;

    // workspace layout (float units, 16B-aligned throughout)
    float* ws = (float*)d_ws;
    size_t o = 0;
    unsigned short* modb = (unsigned short*)(ws + o); o += (size_t)N * 384; // [N,768] bf16
    unsigned short* Bbuf = (unsigned short*)(ws + o); o += (size_t)N * 64;  // xm/xm2 bf16
    unsigned short* Qn   = (unsigned short*)(ws + o); o += (size_t)N * 64;  // qn bf16
    unsigned short* Cbuf = (unsigned short*)(ws + o); o += (size_t)N * 256; // qw bf16
    unsigned short* Dbuf = (unsigned short*)(ws + o); o += (size_t)N * 256; // u bf16
    unsigned short* Ebuf = (unsigned short*)(ws + o); o += (size_t)N * 256; // h bf16
    float* Gbuf = ws + o; o += (size_t)N * 128;                             // x1 -> x2 f32
    unsigned char* QKV = (unsigned char*)(ws + o); o += (size_t)N * (QKV_STRIDE_B / 4);
    unsigned short* Wsa_t  = (unsigned short*)(ws + o); o += 1664 * 128 / 2;
    unsigned short* Mcat_t = (unsigned short*)(ws + o); o += 512 * 128 / 2;
    unsigned short* Pcat_t = (unsigned short*)(ws + o); o += 128 * 512 / 2;
    unsigned short* fc1_t  = (unsigned short*)(ws + o); o += 512 * 128 / 2;
    unsigned short* fc2_t  = (unsigned short*)(ws + o); o += 128 * 512 / 2;
    unsigned short* ada_t  = (unsigned short*)(ws + o); o += 768 * 128 / 2;
    float* bsa   = ws + o; o += 1664;
    float* biasM = ws + o; o += 512;
    float* co    = ws + o; o += 128;
    int* count   = (int*)(ws + o); o += N;
    int* base    = (int*)(ws + o); o += N + 4;
    int* cursor  = (int*)(ws + o); o += N;
    int* pre     = (int*)(ws + o); o += N;
    int* bsum    = (int*)(ws + o); o += 32;
    int* csr_src = (int*)(ws + o); o += E;

    const int* src = ei;
    const int* dst = ei + E;
    const int rb128 = (N + 127) / 128;   // 157
    const int rb64  = (N + 63) / 64;     // 313
    const int nScan = (N + 1023) / 1024;

    // ---- weight prep ----
    conv_all<<<1728, 256, 0, stream>>>(sa_q_w, sa_q_b, sa_k_w, sa_k_b,
                                       sa_v_w, sa_v_b, sa_skip_w, sa_skip_b,
                                       fc1_w, fc2_w, ada_w,
                                       Wsa_t, bsa, fc1_t, fc2_t, ada_t);
    prep_weights<<<256, 256, 0, stream>>>(mha_q_w, mha_q_b, mha_k_w, mha_v_w,
                                          mha_v_b, mha_o_w, mha_o_b,
                                          Mcat_t, biasM, Pcat_t, co);

    // ---- CSR build ----
    hipMemsetAsync(count, 0, (size_t)N * sizeof(int), stream);
    count_edges<<<(E + 255) / 256, 256, 0, stream>>>(dst, count, E);
    scan_block<<<nScan, 1024, 0, stream>>>(count, pre, bsum, N);
    scan_tops<<<1, 64, 0, stream>>>(bsum, nScan);
    scan_fix<<<(N + 255) / 256, 256, 0, stream>>>(pre, bsum, count, base, cursor, N);
    scatter_edges<<<(E + 255) / 256, 256, 0, stream>>>(src, dst, cursor, csr_src, E);

    // ---- adaLN: mod = silu(t) @ ada_w + ada_b  (bf16 out) ----
    gemm_mfma<4, 0, 1, 0, 1><<<dim3(rb128, 6), 256, 0, stream>>>(
        t_in, ada_t, ada_b, modb, nullptr, nullptr, N, 128, 768);

    // ---- xm = modulate(ln(x), shift_msa, scale_msa) ----
    ln_mod_kernel<<<(N + 3) / 4, 256, 0, stream>>>(x, modb, 0, 128, Bbuf, N);

    // ---- fused q|kv|skip GEMM -> packed QKV ----
    gemm_mfma<4, 1, 0, 4, 1><<<dim3(rb128, 13), 256, 0, stream>>>(
        Bbuf, Wsa_t, bsa, QKV, nullptr, nullptr, N, 128, 1664);

    // ---- graph attention + residual + fused norm3 -> x1 (f32), qn (bf16) ----
    sa_node_kernel<<<N, 128, 0, stream>>>(QKV, base, csr_src, x, modb,
                                          n3_g, n3_b, Gbuf, Qn);

    // ---- cross attention (folded) ----
    gemm_mfma<4, 1, 0, 0, 1><<<dim3(rb128, 4), 256, 0, stream>>>(
        Qn, Mcat_t, biasM, Cbuf, nullptr, nullptr, N, 128, 512);
    cross_mid_kernel<<<N, 128, 0, stream>>>(te, Cbuf, Dbuf);
    gemm_mfma<2, 1, 0, 2, 0><<<dim3(rb64, 1), 256, 0, stream>>>(
        Dbuf, Pcat_t, co, Gbuf, Gbuf, nullptr, N, 512, 128);   // x2 = x1 + u@Pcat + co

    // ---- MLP ----
    ln_mod_kernel<<<(N + 3) / 4, 256, 0, stream>>>(Gbuf, modb, 384, 512, Bbuf, N);
    gemm_mfma<4, 1, 0, 1, 1><<<dim3(rb128, 4), 256, 0, stream>>>(
        Bbuf, fc1_t, fc1_b, Ebuf, nullptr, nullptr, N, 128, 512);
    gemm_mfma<2, 1, 0, 3, 0><<<dim3(rb64, 1), 256, 0, stream>>>(
        Ebuf, fc2_t, fc2_b, out, Gbuf, modb + 640, N, 512, 128);
}